// Round 16
// baseline (690.891 us; speedup 1.0000x reference)
//
#include <hip/hip_runtime.h>
#include <math.h>

#define D_MODEL 1024
#define D_FF    4096
#define RANK    8
#define BATCH   4
#define SEQ     2048
#define MTOT    (BATCH*SEQ)
#define NHEADS  16
#define HDIM    64

typedef __attribute__((ext_vector_type(8))) __bf16 bf16x8;
typedef __attribute__((ext_vector_type(4))) float f32x4;
typedef __attribute__((ext_vector_type(8))) unsigned short u16x8;
typedef __attribute__((ext_vector_type(4))) unsigned short u16x4;

// hardware RTNE f32->bf16 (v_cvt on gfx950)
__device__ __forceinline__ unsigned short f2bf(float f) {
  __bf16 h = (__bf16)f;
  return __builtin_bit_cast(unsigned short, h);
}
__device__ __forceinline__ float bf2f(unsigned short h) {
  union { unsigned int u; float f; } v; v.u = ((unsigned int)h) << 16;
  return v.f;
}

__device__ __forceinline__ f32x4 mfma16(bf16x8 a, bf16x8 b, f32x4 c) {
  return __builtin_amdgcn_mfma_f32_16x16x32_bf16(a, b, c, 0, 0, 0);
}

// tanh-form GELU via exp2+rcp (~7 VALU ops vs ~28 for erff; max err ~1e-4,
// an order below bf16 output rounding): gelu = x / (1 + exp2(x*(a + b*x^2)))
// with a = -2*log2e*0.7978845608, b = -2*log2e*0.0356774081.
__device__ __forceinline__ float gelu_fast(float x) {
  const float xx = x * x;
  const float wexp = x * (-2.3022082f + (-0.1029435f) * xx);
  return x * __builtin_amdgcn_rcpf(1.f + __builtin_exp2f(wexp));
}

#define GLDS(g, l) __builtin_amdgcn_global_load_lds( \
    (const __attribute__((address_space(1))) void*)(g), \
    (__attribute__((address_space(3))) void*)(l), 16, 0, 0)

// ---------------------------------------------------------------- merged f32 -> bf16 convert
__global__ __launch_bounds__(256) void cvt_bf16_all(
    const float* __restrict__ s0, const float* __restrict__ s1,
    const float* __restrict__ s2, const float* __restrict__ s3,
    const float* __restrict__ s4, const float* __restrict__ s5,
    unsigned short* __restrict__ d0, unsigned short* __restrict__ d1,
    unsigned short* __restrict__ d2, unsigned short* __restrict__ d3,
    unsigned short* __restrict__ d4, unsigned short* __restrict__ d5)
{
  const int b = blockIdx.x;
  const float* src; unsigned short* dst; int base;
  if (b < 512)       { src = s0; dst = d0; base = b; }
  else if (b < 1024) { src = s1; dst = d1; base = b - 512; }
  else if (b < 1536) { src = s2; dst = d2; base = b - 1024; }
  else if (b < 2048) { src = s3; dst = d3; base = b - 1536; }
  else if (b < 4096) { src = s4; dst = d4; base = b - 2048; }
  else               { src = s5; dst = d5; base = b - 4096; }
  const size_t i = (size_t)base * 256 + threadIdx.x;
  const float4 a  = *reinterpret_cast<const float4*>(src + i * 8);
  const float4 c  = *reinterpret_cast<const float4*>(src + i * 8 + 4);
  u16x8 o;
  o[0] = f2bf(a.x); o[1] = f2bf(a.y); o[2] = f2bf(a.z); o[3] = f2bf(a.w);
  o[4] = f2bf(c.x); o[5] = f2bf(c.y); o[6] = f2bf(c.z); o[7] = f2bf(c.w);
  *reinterpret_cast<u16x8*>(dst + i * 8) = o;
}

// ---------------------------------------------------------------- layernorm (fp32 in, bf16 out)
__global__ __launch_bounds__(256) void ln_fwd(const float* __restrict__ x,
                                              const float* __restrict__ g,
                                              const float* __restrict__ be,
                                              unsigned short* __restrict__ out)
{
  const int row = blockIdx.x;
  const int t = threadIdx.x;
  const float* xr = x + (size_t)row * D_MODEL;
  float4 vv = *reinterpret_cast<const float4*>(xr + t * 4);
  float s  = vv.x + vv.y + vv.z + vv.w;
  float s2 = vv.x * vv.x + vv.y * vv.y + vv.z * vv.z + vv.w * vv.w;
#pragma unroll
  for (int mm = 1; mm < 64; mm <<= 1) { s += __shfl_xor(s, mm); s2 += __shfl_xor(s2, mm); }
  __shared__ float red[8];
  const int w = t >> 6, l = t & 63;
  if (l == 0) { red[w] = s; red[4 + w] = s2; }
  __syncthreads();
  s  = red[0] + red[1] + red[2] + red[3];
  s2 = red[4] + red[5] + red[6] + red[7];
  float mean = s * (1.f / D_MODEL);
  float var  = s2 * (1.f / D_MODEL) - mean * mean;
  float rstd = rsqrtf(var + 1e-5f);
  float4 gv = *reinterpret_cast<const float4*>(g  + t * 4);
  float4 bv = *reinterpret_cast<const float4*>(be + t * 4);
  u16x4 o;
  o[0] = f2bf((vv.x - mean) * rstd * gv.x + bv.x);
  o[1] = f2bf((vv.y - mean) * rstd * gv.y + bv.y);
  o[2] = f2bf((vv.z - mean) * rstd * gv.z + bv.z);
  o[3] = f2bf((vv.w - mean) * rstd * gv.w + bv.w);
  *reinterpret_cast<u16x4*>(out + (size_t)row * D_MODEL + t * 4) = o;
}

// ---------------------------------------------------------------- u[m][r] = sum_i h[m][i]*dyn[b][r][i]
// 8-wide vectorized loads (u16x8 for h, float4 pairs for dyn); lane l owns
// cols l*8..l*8+7 of each 512-col stripe.
template<int ILEN>
__global__ __launch_bounds__(256) void dyn_u(const unsigned short* __restrict__ hmat,
                                             const float* __restrict__ dyn,
                                             float* __restrict__ u)
{
  const int tid = threadIdx.x, w = tid >> 6, l = tid & 63;
  const int m0 = blockIdx.x * 16 + w * 4;
  const int b = m0 / SEQ;
  const float* dynb = dyn + (size_t)b * RANK * ILEN;
  float acc[4][RANK] = {};
#pragma unroll
  for (int s = 0; s < ILEN / 512; ++s) {
    const int i = s * 512 + l * 8;
    float hv[4][8];
#pragma unroll
    for (int rr = 0; rr < 4; ++rr) {
      u16x8 hraw = *reinterpret_cast<const u16x8*>(&hmat[(size_t)(m0 + rr) * ILEN + i]);
#pragma unroll
      for (int e = 0; e < 8; ++e) hv[rr][e] = bf2f(hraw[e]);
    }
#pragma unroll
    for (int r = 0; r < RANK; ++r) {
      float4 d0 = *reinterpret_cast<const float4*>(&dynb[(size_t)r * ILEN + i]);
      float4 d1 = *reinterpret_cast<const float4*>(&dynb[(size_t)r * ILEN + i + 4]);
      const float d[8] = {d0.x, d0.y, d0.z, d0.w, d1.x, d1.y, d1.z, d1.w};
#pragma unroll
      for (int rr = 0; rr < 4; ++rr)
#pragma unroll
        for (int e = 0; e < 8; ++e) acc[rr][r] += hv[rr][e] * d[e];
    }
  }
#pragma unroll
  for (int rr = 0; rr < 4; ++rr)
#pragma unroll
    for (int r = 0; r < RANK; ++r) {
      float a = acc[rr][r];
#pragma unroll
      for (int mm = 1; mm < 64; mm <<= 1) a += __shfl_xor(a, mm);
      if (l == 0) u[(size_t)(m0 + rr) * RANK + r] = a;
    }
}

// fused q/k/v u-computation: reads h once, produces u[3][MTOT][RANK]
__global__ __launch_bounds__(256) void dyn_u_qkv(const unsigned short* __restrict__ hmat,
                                                 const float* __restrict__ dq,
                                                 const float* __restrict__ dk,
                                                 const float* __restrict__ dv,
                                                 float* __restrict__ u)
{
  const int tid = threadIdx.x, w = tid >> 6, l = tid & 63;
  const int m0 = blockIdx.x * 16 + w * 4;
  const int b = m0 / SEQ;
  const float* db0 = dq + (size_t)b * RANK * D_MODEL;
  const float* db1 = dk + (size_t)b * RANK * D_MODEL;
  const float* db2 = dv + (size_t)b * RANK * D_MODEL;
  float acc[4][3 * RANK] = {};
  for (int s = 0; s < D_MODEL / 64; ++s) {
    const int i = l + s * 64;
    float hv[4];
#pragma unroll
    for (int rr = 0; rr < 4; ++rr) hv[rr] = bf2f(hmat[(size_t)(m0 + rr) * D_MODEL + i]);
#pragma unroll
    for (int r = 0; r < RANK; ++r) {
      float d0 = db0[(size_t)r * D_MODEL + i];
      float d1 = db1[(size_t)r * D_MODEL + i];
      float d2 = db2[(size_t)r * D_MODEL + i];
#pragma unroll
      for (int rr = 0; rr < 4; ++rr) {
        acc[rr][r] += hv[rr] * d0;
        acc[rr][RANK + r] += hv[rr] * d1;
        acc[rr][2 * RANK + r] += hv[rr] * d2;
      }
    }
  }
#pragma unroll
  for (int g = 0; g < 3; ++g)
#pragma unroll
    for (int rr = 0; rr < 4; ++rr)
#pragma unroll
      for (int r = 0; r < RANK; ++r) {
        float a = acc[rr][g * RANK + r];
#pragma unroll
        for (int mm = 1; mm < 64; mm <<= 1) a += __shfl_xor(a, mm);
        if (l == 0) u[((size_t)g * MTOT + m0 + rr) * RANK + r] = a;
      }
}

// ---------------------------------------------------------------- GEMM  C[m,n] = sum_k A[m,k]*B[n,k] (+epilogue)
// Round-11 proven config: BM=256, BN templated (128/256), BK=64, 8 waves,
// 2-buffer LDS, prefetch-before-compute.
// MODE 1: +resid(fp32), fp32 out (Wo)
// MODE 2: +dyn delta +bias, fast-gelu, bf16 out (FF1)
// MODE 3: +dyn delta +bias +resid, fp32 out (FF2)
// MODE 5: fused QKV -> {Q (pre-scaled), K, V transposed+key-permuted to vt}
template<int NDIM, int KDIM, int MODE, int BN>
__global__ __launch_bounds__(512, (BN == 256) ? 1 : 2)
void gemm_bt(const unsigned short* __restrict__ A,
             const unsigned short* __restrict__ B,
             void* __restrict__ outp,
             void* __restrict__ outp2,
             const float* __restrict__ uvec,
             const float* __restrict__ Ad0,
             const float* __restrict__ Ad1,
             const float* __restrict__ Ad2,
             const float* __restrict__ bias,
             const float* __restrict__ resid)
{
  constexpr bool HAS_DYN = (MODE == 2 || MODE == 3 || MODE == 5);
  constexpr int WN = BN / 64;       // waves along N
  constexpr int WM = 8 / WN;        // waves along M
  constexpr int MSPAN = 256 / WM;   // per-wave M extent
  constexpr int NI = MSPAN / 16;    // M-fragments per wave
  __shared__ unsigned short sAB[2][(256 + BN) * 64];
  const int tid = threadIdx.x;
  const int w = tid >> 6, l = tid & 63;

  constexpr int NBX = NDIM / BN;
  constexpr int NWG = NBX * (MTOT / 256);
  const int bid = blockIdx.y * NBX + blockIdx.x;
  const int sbid = (bid & 7) * (NWG / 8) + (bid >> 3);
  const int tm = (sbid / NBX) * 256, tn = (sbid % NBX) * BN;
  const int wm = w / WN, wn = w % WN;

  f32x4 acc[NI][4] = {};

  const int srow = l >> 3;
  const int sc8 = (l & 7) ^ (srow & 7);
  const unsigned short* Ag = A + (size_t)(tm + srow) * KDIM + sc8 * 8;
  const unsigned short* Bg = B + (size_t)(tn + srow) * KDIM + sc8 * 8;

  const int arow = wm * MSPAN + (l & 15);
  const int bcol = wn * 64 + (l & 15);
  const int kb0 = l >> 4;
  const int swz = l & 7;

  constexpr int NT = KDIM / 64;

  auto stage = [&](int buf, int kt) {
    unsigned short* bA = &sAB[buf][0];
    unsigned short* bB = &sAB[buf][256 * 64];
#pragma unroll
    for (int it = 0; it < 4; ++it) {
      const int st = w * 4 + it;
      GLDS(Ag + (size_t)(st * 8) * KDIM + kt, bA + st * 512);
    }
#pragma unroll
    for (int it = 0; it < WN; ++it) {
      const int st = w * WN + it;
      GLDS(Bg + (size_t)(st * 8) * KDIM + kt, bB + st * 512);
    }
  };

  stage(0, 0);
  asm volatile("s_waitcnt vmcnt(0)" ::: "memory");
  __syncthreads();

  int cur = 0;
  for (int t = 0; t < NT; ++t) {
    if (t + 1 < NT) stage(cur ^ 1, (t + 1) * 64);

    const unsigned short* sA_ = &sAB[cur][0];
    const unsigned short* sB_ = &sAB[cur][256 * 64];
#pragma unroll
    for (int kk = 0; kk < 2; ++kk) {
      bf16x8 af[NI], bfv[4];
      const int kphys = ((kk * 4 + kb0) ^ swz) << 3;
#pragma unroll
      for (int i = 0; i < NI; ++i)
        af[i] = *reinterpret_cast<const bf16x8*>(&sA_[(arow + i * 16) * 64 + kphys]);
#pragma unroll
      for (int j = 0; j < 4; ++j)
        bfv[j] = *reinterpret_cast<const bf16x8*>(&sB_[(bcol + j * 16) * 64 + kphys]);
#pragma unroll
      for (int i = 0; i < NI; ++i)
#pragma unroll
        for (int j = 0; j < 4; ++j)
          acc[i][j] = mfma16(af[i], bfv[j], acc[i][j]);
    }
    __syncthreads();
    cur ^= 1;
  }

  const int rbase = tm + wm * MSPAN + ((l >> 4) << 2);
  const int cbase = tn + wn * 64 + (l & 15);

  const int seg = tn >> 10;   // MODE 5: tiles never cross a 1024 segment
  const float* Ad = Ad0;
  const float* uv = uvec;
  if constexpr (MODE == 5) {
    Ad = (seg == 0) ? Ad0 : (seg == 1) ? Ad1 : Ad2;
    uv = uvec + (size_t)seg * ((size_t)MTOT * RANK);
  }

#pragma unroll
  for (int i = 0; i < NI; ++i) {
    float uu[4][8];
    if constexpr (HAS_DYN) {
#pragma unroll
      for (int r = 0; r < 4; ++r) {
        const float* up = uv + (size_t)(rbase + i * 16 + r) * RANK;
#pragma unroll
        for (int p = 0; p < 8; ++p) uu[r][p] = up[p];
      }
    }
#pragma unroll
    for (int j = 0; j < 4; ++j) {
      const int col = cbase + j * 16;
      float ad[8];
      if constexpr (HAS_DYN) {
#pragma unroll
        for (int p = 0; p < 8; ++p) ad[p] = Ad[(size_t)col * RANK + p];
      }
      float vv4[4];
#pragma unroll
      for (int r = 0; r < 4; ++r) {
        const int row = rbase + i * 16 + r;
        float v = acc[i][j][r];
        if constexpr (HAS_DYN) {
#pragma unroll
          for (int p = 0; p < 8; ++p) v += uu[r][p] * ad[p];
        }
        if constexpr (MODE == 2) {
          v = gelu_fast(v + bias[col]);
        }
        if constexpr (MODE == 1) {
          v += resid[(size_t)row * NDIM + col];
        }
        if constexpr (MODE == 3) {
          v += bias[col] + resid[(size_t)row * NDIM + col];
        }
        if constexpr (MODE == 5) {
          if (seg == 0) v *= 0.18033688011112042f;  // 0.125 * log2(e)
        }
        vv4[r] = v;
      }
      if constexpr (MODE == 2) {
#pragma unroll
        for (int r = 0; r < 4; ++r)
          ((unsigned short*)outp)[(size_t)(rbase + i * 16 + r) * NDIM + col] = f2bf(vv4[r]);
      } else if constexpr (MODE == 5) {
        const int cl = col & 1023;
        if (seg < 2) {
#pragma unroll
          for (int r = 0; r < 4; ++r)
            ((unsigned short*)outp)[((size_t)seg * MTOT + rbase + i * 16 + r) * D_MODEL + cl] =
                f2bf(vv4[r]);
        } else {
          // vt[b][h][d][t'] key-permuted: token k -> slot (k&15)*4 + ((k>>4)&3)
          const int row0 = rbase + i * 16;
          const int bb = row0 >> 11, t0 = row0 & (SEQ - 1);
          const int hh = cl >> 6, dd = cl & 63;
          const int jj = (t0 >> 4) & 3;
          unsigned short* vb = &((unsigned short*)outp2)[
              (((size_t)bb * NHEADS + hh) * HDIM + dd) * SEQ + (t0 & ~63)];
#pragma unroll
          for (int dlt = 0; dlt < 4; ++dlt)
            vb[((t0 & 15) + dlt) * 4 + jj] = f2bf(vv4[dlt]);
        }
      } else {
#pragma unroll
        for (int r = 0; r < 4; ++r)
          ((float*)outp)[(size_t)(rbase + i * 16 + r) * NDIM + col] = vv4[r];
      }
    }
  }
}

// ---------------------------------------------------------------- flash attention (non-causal)
// Round-15 version: max-free + ones-MFMA softmax, KVBLK=64, 32KB LDS ->
// 4 blocks/CU = 16 waves/CU.
__global__ __launch_bounds__(256, 4) void attn_fwd(const unsigned short* __restrict__ q,
                                                   const unsigned short* __restrict__ k,
                                                   const unsigned short* __restrict__ vt,
                                                   unsigned short* __restrict__ ctx)
{
  __shared__ unsigned short sK[64 * 64];
  __shared__ unsigned short sV[64 * 64];
  __shared__ unsigned short sP[4][32 * 64];

  const int tid = threadIdx.x, w = tid >> 6, l = tid & 63;
  const int lin = blockIdx.y * (SEQ / 128) + blockIdx.x;
  const int W = (lin & 7) * ((BATCH * NHEADS * SEQ / 128) / 8) + (lin >> 3);
  const int bh = W >> 4, b = bh >> 4, hh = bh & 15;
  const int q0 = (W & 15) * 128 + w * 32;
  const size_t base = ((size_t)b * SEQ) * D_MODEL + hh * HDIM;
  const size_t vtbase = (size_t)bh * HDIM * SEQ;

  bf16x8 qf[2][2];
#pragma unroll
  for (int i = 0; i < 2; ++i)
#pragma unroll
    for (int ks = 0; ks < 2; ++ks)
      qf[i][ks] = *reinterpret_cast<const bf16x8*>(
          &q[base + (size_t)(q0 + i * 16 + (l & 15)) * D_MODEL + ks * 32 + (l >> 4) * 8]);

  bf16x8 ones;
#pragma unroll
  for (int e = 0; e < 8; ++e) ones[e] = (__bf16)1.0f;

  f32x4 oacc[2][4] = {};
  f32x4 sumacc[2] = {};

  const int srow8 = l >> 3;
  const int sswz = (l & 7) ^ (srow8 & 7);
  const unsigned short* kg = k + base + (size_t)srow8 * D_MODEL + sswz * 8;
  const unsigned short* vg = vt + vtbase + (size_t)srow8 * SEQ + sswz * 8;

  const int kb0 = l >> 4;
  const int c15 = l & 15;

  for (int kt = 0; kt < SEQ; kt += 64) {
    __syncthreads();
#pragma unroll
    for (int it = 0; it < 2; ++it) {
      const int c = it * 4 + w;
      GLDS(kg + (size_t)(kt + c * 8) * D_MODEL, sK + c * 512);
      GLDS(vg + (size_t)(c * 8) * SEQ + kt, sV + c * 512);
    }
    asm volatile("s_waitcnt vmcnt(0)" ::: "memory");
    __syncthreads();

    // S = Q K^T  (64 keys = 4 j-blocks); scores already in log2 domain
    f32x4 sacc[2][4] = {};
    __builtin_amdgcn_s_setprio(1);
#pragma unroll
    for (int ks = 0; ks < 2; ++ks) {
#pragma unroll
      for (int j = 0; j < 4; ++j) {
        const int row = j * 16 + (l & 15);
        bf16x8 kf = *reinterpret_cast<const bf16x8*>(
            &sK[row * 64 + (((ks * 4 + kb0) ^ (row & 7)) << 3)]);
#pragma unroll
        for (int i = 0; i < 2; ++i) sacc[i][j] = mfma16(qf[i][ks], kf, sacc[i][j]);
      }
    }
    __builtin_amdgcn_s_setprio(0);

    // max-free softmax: p = exp2(s); denominator via ones-MFMA in PV phase.
#pragma unroll
    for (int i = 0; i < 2; ++i) {
#pragma unroll
      for (int r = 0; r < 4; ++r) {
        float p[4];
#pragma unroll
        for (int j = 0; j < 4; ++j) p[j] = __builtin_exp2f(sacc[i][j][r]);
        const int prow = i * 16 + ((l >> 4) << 2) + r;
        u16x4 pk;
        pk[0] = f2bf(p[0]); pk[1] = f2bf(p[1]); pk[2] = f2bf(p[2]); pk[3] = f2bf(p[3]);
        *reinterpret_cast<u16x4*>(
            &sP[w][prow * 64 + ((((c15 >> 1) ^ (prow & 7)) << 3) | ((c15 & 1) << 2))]) = pk;
      }
    }

    // O += P V ; rowsum += P * ones
    __builtin_amdgcn_s_setprio(1);
#pragma unroll
    for (int ks = 0; ks < 2; ++ks) {
      bf16x8 pf[2];
#pragma unroll
      for (int i = 0; i < 2; ++i) {
        const int prw = i * 16 + (l & 15);
        pf[i] = *reinterpret_cast<const bf16x8*>(
            &sP[w][prw * 64 + (((ks * 4 + kb0) ^ (prw & 7)) << 3)]);
      }
#pragma unroll
      for (int j = 0; j < 4; ++j) {
        const int row = j * 16 + (l & 15);
        bf16x8 vf = *reinterpret_cast<const bf16x8*>(
            &sV[row * 64 + (((ks * 4 + kb0) ^ (row & 7)) << 3)]);
#pragma unroll
        for (int i = 0; i < 2; ++i) oacc[i][j] = mfma16(pf[i], vf, oacc[i][j]);
      }
#pragma unroll
      for (int i = 0; i < 2; ++i) sumacc[i] = mfma16(pf[i], ones, sumacc[i]);
    }
    __builtin_amdgcn_s_setprio(0);
  }

#pragma unroll
  for (int i = 0; i < 2; ++i)
#pragma unroll
    for (int r = 0; r < 4; ++r) {
      float inv = 1.f / sumacc[i][r];
      int row = q0 + i * 16 + ((l >> 4) << 2) + r;
#pragma unroll
      for (int j = 0; j < 4; ++j)
        ctx[base + (size_t)row * D_MODEL + j * 16 + (l & 15)] = f2bf(oacc[i][j][r] * inv);
    }
}

// ---------------------------------------------------------------- launch
extern "C" void kernel_launch(void* const* d_in, const int* in_sizes, int n_in,
                              void* d_out, int out_size, void* d_ws, size_t ws_size,
                              hipStream_t stream)
{
  (void)in_sizes; (void)n_in; (void)out_size; (void)ws_size;
  const float* x      = (const float*)d_in[0];
  const float* dyn_q  = (const float*)d_in[1];
  const float* dyn_k  = (const float*)d_in[2];
  const float* dyn_v  = (const float*)d_in[3];
  const float* dyn_f1 = (const float*)d_in[4];
  const float* dyn_f2 = (const float*)d_in[5];
  const float* Wq = (const float*)d_in[6];
  const float* Aq = (const float*)d_in[7];
  const float* Wk = (const float*)d_in[8];
  const float* Ak = (const float*)d_in[9];
  const float* Wv = (const float*)d_in[10];
  const float* Av = (const float*)d_in[11];
  const float* Wo = (const float*)d_in[12];
  const float* W1 = (const float*)d_in[13];
  const float* b1 = (const float*)d_in[14];
  const float* A1 = (const float*)d_in[15];
  const float* W2 = (const float*)d_in[16];
  const float* b2 = (const float*)d_in[17];
  const float* A2 = (const float*)d_in[18];
  const float* g1 = (const float*)d_in[19];
  const float* be1 = (const float*)d_in[20];
  const float* g2 = (const float*)d_in[21];
  const float* be2 = (const float*)d_in[22];

  char* ws = (char*)d_ws;
  size_t o = 0;
  auto take = [&](size_t b) { size_t r = o; o += (b + 255) & ~(size_t)255; return r; };
  const size_t o_wq = take((size_t)D_MODEL * D_MODEL * 2);  // wq,wk,wv contiguous (2MB each)
  const size_t o_wk = take((size_t)D_MODEL * D_MODEL * 2);
  const size_t o_wv = take((size_t)D_MODEL * D_MODEL * 2);
  const size_t o_wo = take((size_t)D_MODEL * D_MODEL * 2);
  const size_t o_w1 = take((size_t)D_FF * D_MODEL * 2);
  const size_t o_w2 = take((size_t)D_FF * D_MODEL * 2);
  const size_t o_h1 = take((size_t)MTOT * D_MODEL * 2);   // later reused as ctx
  const size_t o_q  = take((size_t)MTOT * D_MODEL * 2);   // q,k contiguous; later x2
  const size_t o_k  = take((size_t)MTOT * D_MODEL * 2);
  const size_t o_v  = take((size_t)MTOT * D_MODEL * 2);   // vt; later reused as h2
  const size_t o_u  = take((size_t)MTOT * RANK * 4 * 3);  // u_q,u_k,u_v contiguous
  const size_t o_ff = take((size_t)MTOT * D_FF * 2);

  unsigned short* wq_b = (unsigned short*)(ws + o_wq);
  unsigned short* wk_b = (unsigned short*)(ws + o_wk);
  unsigned short* wv_b = (unsigned short*)(ws + o_wv);
  unsigned short* wo_b = (unsigned short*)(ws + o_wo);
  unsigned short* w1_b = (unsigned short*)(ws + o_w1);
  unsigned short* w2_b = (unsigned short*)(ws + o_w2);
  unsigned short* h1   = (unsigned short*)(ws + o_h1);
  unsigned short* qb   = (unsigned short*)(ws + o_q);
  unsigned short* vtb  = (unsigned short*)(ws + o_v);
  float* u_q  = (float*)(ws + o_u);
  float* u_k  = u_q + (size_t)MTOT * RANK;
  unsigned short* ctx = h1;                    // reuse
  float* x2 = (float*)(ws + o_q);              // reuse q+k (32MB)
  unsigned short* h2 = vtb;                    // reuse
  float* u_f1 = u_q;                           // reuse
  float* u_f2 = u_k;                           // reuse
  unsigned short* ffb = (unsigned short*)(ws + o_ff);

  // 1. weights -> bf16 (single merged launch)
  cvt_bf16_all<<<6144, 256, 0, stream>>>(Wq, Wk, Wv, Wo, W1, W2,
                                         wq_b, wk_b, wv_b, wo_b, w1_b, w2_b);

  // 2. LN1
  ln_fwd<<<MTOT, 256, 0, stream>>>(x, g1, be1, h1);

  // 3. dynamic u for q,k,v (fused, reads h1 once)
  dyn_u_qkv<<<MTOT / 16, 256, 0, stream>>>(h1, dyn_q, dyn_k, dyn_v, u_q);

  // 4. fused QKV projection (BN=256; Q pre-scaled, V pre-transposed+key-permuted)
  gemm_bt<3 * D_MODEL, D_MODEL, 5, 256><<<dim3(3 * D_MODEL / 256, MTOT / 256), 512, 0, stream>>>(
      h1, wq_b, qb, vtb, u_q, Aq, Ak, Av, nullptr, nullptr);

  // 5. attention
  attn_fwd<<<dim3(SEQ / 128, BATCH * NHEADS), 256, 0, stream>>>(
      qb, qb + (size_t)MTOT * D_MODEL, vtb, ctx);

  // 6. Wo + residual -> x2 (fp32), BN=128
  gemm_bt<D_MODEL, D_MODEL, 1, 128><<<dim3(D_MODEL / 128, MTOT / 256), 512, 0, stream>>>(
      ctx, wo_b, x2, nullptr, nullptr, nullptr, nullptr, nullptr, nullptr, x);

  // 7. LN2
  ln_fwd<<<MTOT, 256, 0, stream>>>(x2, g2, be2, h2);

  // 8. u_ff1, FF1 (+bias,+delta,fast-gelu) -> ff bf16, BN=256
  dyn_u<D_MODEL><<<MTOT / 16, 256, 0, stream>>>(h2, dyn_f1, u_f1);
  gemm_bt<D_FF, D_MODEL, 2, 256><<<dim3(D_FF / 256, MTOT / 256), 512, 0, stream>>>(
      h2, w1_b, ffb, nullptr, u_f1, A1, nullptr, nullptr, b1, nullptr);

  // 9. u_ff2, FF2 (+bias,+delta,+resid) -> out fp32, BN=128
  dyn_u<D_FF><<<MTOT / 16, 256, 0, stream>>>(ffb, dyn_f2, u_f2);
  gemm_bt<D_MODEL, D_FF, 3, 128><<<dim3(D_MODEL / 128, MTOT / 256), 512, 0, stream>>>(
      ffb, w2_b, (float*)d_out, nullptr, u_f2, A2, nullptr, nullptr, b2, x2);
}

// Round 17
// 656.863 us; speedup vs baseline: 1.0518x; 1.0518x over previous
//
#include <hip/hip_runtime.h>
#include <math.h>

#define D_MODEL 1024
#define D_FF    4096
#define RANK    8
#define BATCH   4
#define SEQ     2048
#define MTOT    (BATCH*SEQ)
#define NHEADS  16
#define HDIM    64

typedef __attribute__((ext_vector_type(8))) __bf16 bf16x8;
typedef __attribute__((ext_vector_type(4))) float f32x4;
typedef __attribute__((ext_vector_type(8))) unsigned short u16x8;
typedef __attribute__((ext_vector_type(4))) unsigned short u16x4;

// hardware RTNE f32->bf16 (v_cvt on gfx950)
__device__ __forceinline__ unsigned short f2bf(float f) {
  __bf16 h = (__bf16)f;
  return __builtin_bit_cast(unsigned short, h);
}
__device__ __forceinline__ float bf2f(unsigned short h) {
  union { unsigned int u; float f; } v; v.u = ((unsigned int)h) << 16;
  return v.f;
}

__device__ __forceinline__ f32x4 mfma16(bf16x8 a, bf16x8 b, f32x4 c) {
  return __builtin_amdgcn_mfma_f32_16x16x32_bf16(a, b, c, 0, 0, 0);
}

#define GLDS(g, l) __builtin_amdgcn_global_load_lds( \
    (const __attribute__((address_space(1))) void*)(g), \
    (__attribute__((address_space(3))) void*)(l), 16, 0, 0)

// ---------------------------------------------------------------- merged f32 -> bf16 convert
__global__ __launch_bounds__(256) void cvt_bf16_all(
    const float* __restrict__ s0, const float* __restrict__ s1,
    const float* __restrict__ s2, const float* __restrict__ s3,
    const float* __restrict__ s4, const float* __restrict__ s5,
    unsigned short* __restrict__ d0, unsigned short* __restrict__ d1,
    unsigned short* __restrict__ d2, unsigned short* __restrict__ d3,
    unsigned short* __restrict__ d4, unsigned short* __restrict__ d5)
{
  const int b = blockIdx.x;
  const float* src; unsigned short* dst; int base;
  if (b < 512)       { src = s0; dst = d0; base = b; }
  else if (b < 1024) { src = s1; dst = d1; base = b - 512; }
  else if (b < 1536) { src = s2; dst = d2; base = b - 1024; }
  else if (b < 2048) { src = s3; dst = d3; base = b - 1536; }
  else if (b < 4096) { src = s4; dst = d4; base = b - 2048; }
  else               { src = s5; dst = d5; base = b - 4096; }
  const size_t i = (size_t)base * 256 + threadIdx.x;
  const float4 a  = *reinterpret_cast<const float4*>(src + i * 8);
  const float4 c  = *reinterpret_cast<const float4*>(src + i * 8 + 4);
  u16x8 o;
  o[0] = f2bf(a.x); o[1] = f2bf(a.y); o[2] = f2bf(a.z); o[3] = f2bf(a.w);
  o[4] = f2bf(c.x); o[5] = f2bf(c.y); o[6] = f2bf(c.z); o[7] = f2bf(c.w);
  *reinterpret_cast<u16x8*>(dst + i * 8) = o;
}

// ---------------------------------------------------------------- layernorm (fp32 in, bf16 out)
__global__ __launch_bounds__(256) void ln_fwd(const float* __restrict__ x,
                                              const float* __restrict__ g,
                                              const float* __restrict__ be,
                                              unsigned short* __restrict__ out)
{
  const int row = blockIdx.x;
  const int t = threadIdx.x;
  const float* xr = x + (size_t)row * D_MODEL;
  float4 vv = *reinterpret_cast<const float4*>(xr + t * 4);
  float s  = vv.x + vv.y + vv.z + vv.w;
  float s2 = vv.x * vv.x + vv.y * vv.y + vv.z * vv.z + vv.w * vv.w;
#pragma unroll
  for (int mm = 1; mm < 64; mm <<= 1) { s += __shfl_xor(s, mm); s2 += __shfl_xor(s2, mm); }
  __shared__ float red[8];
  const int w = t >> 6, l = t & 63;
  if (l == 0) { red[w] = s; red[4 + w] = s2; }
  __syncthreads();
  s  = red[0] + red[1] + red[2] + red[3];
  s2 = red[4] + red[5] + red[6] + red[7];
  float mean = s * (1.f / D_MODEL);
  float var  = s2 * (1.f / D_MODEL) - mean * mean;
  float rstd = rsqrtf(var + 1e-5f);
  float4 gv = *reinterpret_cast<const float4*>(g  + t * 4);
  float4 bv = *reinterpret_cast<const float4*>(be + t * 4);
  u16x4 o;
  o[0] = f2bf((vv.x - mean) * rstd * gv.x + bv.x);
  o[1] = f2bf((vv.y - mean) * rstd * gv.y + bv.y);
  o[2] = f2bf((vv.z - mean) * rstd * gv.z + bv.z);
  o[3] = f2bf((vv.w - mean) * rstd * gv.w + bv.w);
  *reinterpret_cast<u16x4*>(out + (size_t)row * D_MODEL + t * 4) = o;
}

// ---------------------------------------------------------------- u[m][r] = sum_i h[m][i]*dyn[b][r][i]
// 8-wide vectorized loads (u16x8 for h, float4 pairs for dyn); lane l owns
// cols l*8..l*8+7 of each 512-col stripe.
template<int ILEN>
__global__ __launch_bounds__(256) void dyn_u(const unsigned short* __restrict__ hmat,
                                             const float* __restrict__ dyn,
                                             float* __restrict__ u)
{
  const int tid = threadIdx.x, w = tid >> 6, l = tid & 63;
  const int m0 = blockIdx.x * 16 + w * 4;
  const int b = m0 / SEQ;
  const float* dynb = dyn + (size_t)b * RANK * ILEN;
  float acc[4][RANK] = {};
#pragma unroll
  for (int s = 0; s < ILEN / 512; ++s) {
    const int i = s * 512 + l * 8;
    float hv[4][8];
#pragma unroll
    for (int rr = 0; rr < 4; ++rr) {
      u16x8 hraw = *reinterpret_cast<const u16x8*>(&hmat[(size_t)(m0 + rr) * ILEN + i]);
#pragma unroll
      for (int e = 0; e < 8; ++e) hv[rr][e] = bf2f(hraw[e]);
    }
#pragma unroll
    for (int r = 0; r < RANK; ++r) {
      float4 d0 = *reinterpret_cast<const float4*>(&dynb[(size_t)r * ILEN + i]);
      float4 d1 = *reinterpret_cast<const float4*>(&dynb[(size_t)r * ILEN + i + 4]);
      const float d[8] = {d0.x, d0.y, d0.z, d0.w, d1.x, d1.y, d1.z, d1.w};
#pragma unroll
      for (int rr = 0; rr < 4; ++rr)
#pragma unroll
        for (int e = 0; e < 8; ++e) acc[rr][r] += hv[rr][e] * d[e];
    }
  }
#pragma unroll
  for (int rr = 0; rr < 4; ++rr)
#pragma unroll
    for (int r = 0; r < RANK; ++r) {
      float a = acc[rr][r];
#pragma unroll
      for (int mm = 1; mm < 64; mm <<= 1) a += __shfl_xor(a, mm);
      if (l == 0) u[(size_t)(m0 + rr) * RANK + r] = a;
    }
}

// fused q/k/v u-computation: reads h once, produces u[3][MTOT][RANK]
__global__ __launch_bounds__(256) void dyn_u_qkv(const unsigned short* __restrict__ hmat,
                                                 const float* __restrict__ dq,
                                                 const float* __restrict__ dk,
                                                 const float* __restrict__ dv,
                                                 float* __restrict__ u)
{
  const int tid = threadIdx.x, w = tid >> 6, l = tid & 63;
  const int m0 = blockIdx.x * 16 + w * 4;
  const int b = m0 / SEQ;
  const float* db0 = dq + (size_t)b * RANK * D_MODEL;
  const float* db1 = dk + (size_t)b * RANK * D_MODEL;
  const float* db2 = dv + (size_t)b * RANK * D_MODEL;
  float acc[4][3 * RANK] = {};
  for (int s = 0; s < D_MODEL / 64; ++s) {
    const int i = l + s * 64;
    float hv[4];
#pragma unroll
    for (int rr = 0; rr < 4; ++rr) hv[rr] = bf2f(hmat[(size_t)(m0 + rr) * D_MODEL + i]);
#pragma unroll
    for (int r = 0; r < RANK; ++r) {
      float d0 = db0[(size_t)r * D_MODEL + i];
      float d1 = db1[(size_t)r * D_MODEL + i];
      float d2 = db2[(size_t)r * D_MODEL + i];
#pragma unroll
      for (int rr = 0; rr < 4; ++rr) {
        acc[rr][r] += hv[rr] * d0;
        acc[rr][RANK + r] += hv[rr] * d1;
        acc[rr][2 * RANK + r] += hv[rr] * d2;
      }
    }
  }
#pragma unroll
  for (int g = 0; g < 3; ++g)
#pragma unroll
    for (int rr = 0; rr < 4; ++rr)
#pragma unroll
      for (int r = 0; r < RANK; ++r) {
        float a = acc[rr][g * RANK + r];
#pragma unroll
        for (int mm = 1; mm < 64; mm <<= 1) a += __shfl_xor(a, mm);
        if (l == 0) u[((size_t)g * MTOT + m0 + rr) * RANK + r] = a;
      }
}

// ---------------------------------------------------------------- GEMM  C[m,n] = sum_k A[m,k]*B[n,k] (+epilogue)
// Round-15 proven config (exact): BM=256, BN templated (128/256), BK=64,
// 8 waves, 2-buffer LDS, prefetch-before-compute. erff GELU kept: the inline
// fast-gelu (r16) triggered epilogue software-pipelining -> spill (+115MB HBM).
// MODE 1: +resid(fp32), fp32 out (Wo)
// MODE 2: +dyn delta +bias, gelu, bf16 out (FF1)
// MODE 3: +dyn delta +bias +resid, fp32 out (FF2)
// MODE 5: fused QKV -> {Q (pre-scaled), K, V transposed+key-permuted to vt}
template<int NDIM, int KDIM, int MODE, int BN>
__global__ __launch_bounds__(512, (BN == 256) ? 1 : 2)
void gemm_bt(const unsigned short* __restrict__ A,
             const unsigned short* __restrict__ B,
             void* __restrict__ outp,
             void* __restrict__ outp2,
             const float* __restrict__ uvec,
             const float* __restrict__ Ad0,
             const float* __restrict__ Ad1,
             const float* __restrict__ Ad2,
             const float* __restrict__ bias,
             const float* __restrict__ resid)
{
  constexpr bool HAS_DYN = (MODE == 2 || MODE == 3 || MODE == 5);
  constexpr int WN = BN / 64;       // waves along N
  constexpr int WM = 8 / WN;        // waves along M
  constexpr int MSPAN = 256 / WM;   // per-wave M extent
  constexpr int NI = MSPAN / 16;    // M-fragments per wave
  __shared__ unsigned short sAB[2][(256 + BN) * 64];
  const int tid = threadIdx.x;
  const int w = tid >> 6, l = tid & 63;

  constexpr int NBX = NDIM / BN;
  constexpr int NWG = NBX * (MTOT / 256);
  const int bid = blockIdx.y * NBX + blockIdx.x;
  const int sbid = (bid & 7) * (NWG / 8) + (bid >> 3);
  const int tm = (sbid / NBX) * 256, tn = (sbid % NBX) * BN;
  const int wm = w / WN, wn = w % WN;

  f32x4 acc[NI][4] = {};

  const int srow = l >> 3;
  const int sc8 = (l & 7) ^ (srow & 7);
  const unsigned short* Ag = A + (size_t)(tm + srow) * KDIM + sc8 * 8;
  const unsigned short* Bg = B + (size_t)(tn + srow) * KDIM + sc8 * 8;

  const int arow = wm * MSPAN + (l & 15);
  const int bcol = wn * 64 + (l & 15);
  const int kb0 = l >> 4;
  const int swz = l & 7;

  constexpr int NT = KDIM / 64;

  auto stage = [&](int buf, int kt) {
    unsigned short* bA = &sAB[buf][0];
    unsigned short* bB = &sAB[buf][256 * 64];
#pragma unroll
    for (int it = 0; it < 4; ++it) {
      const int st = w * 4 + it;
      GLDS(Ag + (size_t)(st * 8) * KDIM + kt, bA + st * 512);
    }
#pragma unroll
    for (int it = 0; it < WN; ++it) {
      const int st = w * WN + it;
      GLDS(Bg + (size_t)(st * 8) * KDIM + kt, bB + st * 512);
    }
  };

  stage(0, 0);
  asm volatile("s_waitcnt vmcnt(0)" ::: "memory");
  __syncthreads();

  int cur = 0;
  for (int t = 0; t < NT; ++t) {
    if (t + 1 < NT) stage(cur ^ 1, (t + 1) * 64);

    const unsigned short* sA_ = &sAB[cur][0];
    const unsigned short* sB_ = &sAB[cur][256 * 64];
#pragma unroll
    for (int kk = 0; kk < 2; ++kk) {
      bf16x8 af[NI], bfv[4];
      const int kphys = ((kk * 4 + kb0) ^ swz) << 3;
#pragma unroll
      for (int i = 0; i < NI; ++i)
        af[i] = *reinterpret_cast<const bf16x8*>(&sA_[(arow + i * 16) * 64 + kphys]);
#pragma unroll
      for (int j = 0; j < 4; ++j)
        bfv[j] = *reinterpret_cast<const bf16x8*>(&sB_[(bcol + j * 16) * 64 + kphys]);
#pragma unroll
      for (int i = 0; i < NI; ++i)
#pragma unroll
        for (int j = 0; j < 4; ++j)
          acc[i][j] = mfma16(af[i], bfv[j], acc[i][j]);
    }
    __syncthreads();
    cur ^= 1;
  }

  const int rbase = tm + wm * MSPAN + ((l >> 4) << 2);
  const int cbase = tn + wn * 64 + (l & 15);

  const int seg = tn >> 10;   // MODE 5: tiles never cross a 1024 segment
  const float* Ad = Ad0;
  const float* uv = uvec;
  if constexpr (MODE == 5) {
    Ad = (seg == 0) ? Ad0 : (seg == 1) ? Ad1 : Ad2;
    uv = uvec + (size_t)seg * ((size_t)MTOT * RANK);
  }

#pragma unroll
  for (int i = 0; i < NI; ++i) {
    float uu[4][8];
    if constexpr (HAS_DYN) {
#pragma unroll
      for (int r = 0; r < 4; ++r) {
        const float* up = uv + (size_t)(rbase + i * 16 + r) * RANK;
#pragma unroll
        for (int p = 0; p < 8; ++p) uu[r][p] = up[p];
      }
    }
#pragma unroll
    for (int j = 0; j < 4; ++j) {
      const int col = cbase + j * 16;
      float ad[8];
      if constexpr (HAS_DYN) {
#pragma unroll
        for (int p = 0; p < 8; ++p) ad[p] = Ad[(size_t)col * RANK + p];
      }
      float vv4[4];
#pragma unroll
      for (int r = 0; r < 4; ++r) {
        const int row = rbase + i * 16 + r;
        float v = acc[i][j][r];
        if constexpr (HAS_DYN) {
#pragma unroll
          for (int p = 0; p < 8; ++p) v += uu[r][p] * ad[p];
        }
        if constexpr (MODE == 2) {
          v += bias[col];
          v = 0.5f * v * (1.f + erff(v * 0.70710678118654752f));
        }
        if constexpr (MODE == 1) {
          v += resid[(size_t)row * NDIM + col];
        }
        if constexpr (MODE == 3) {
          v += bias[col] + resid[(size_t)row * NDIM + col];
        }
        if constexpr (MODE == 5) {
          if (seg == 0) v *= 0.18033688011112042f;  // 0.125 * log2(e)
        }
        vv4[r] = v;
      }
      if constexpr (MODE == 2) {
#pragma unroll
        for (int r = 0; r < 4; ++r)
          ((unsigned short*)outp)[(size_t)(rbase + i * 16 + r) * NDIM + col] = f2bf(vv4[r]);
      } else if constexpr (MODE == 5) {
        const int cl = col & 1023;
        if (seg < 2) {
#pragma unroll
          for (int r = 0; r < 4; ++r)
            ((unsigned short*)outp)[((size_t)seg * MTOT + rbase + i * 16 + r) * D_MODEL + cl] =
                f2bf(vv4[r]);
        } else {
          // vt[b][h][d][t'] key-permuted: token k -> slot (k&15)*4 + ((k>>4)&3)
          const int row0 = rbase + i * 16;
          const int bb = row0 >> 11, t0 = row0 & (SEQ - 1);
          const int hh = cl >> 6, dd = cl & 63;
          const int jj = (t0 >> 4) & 3;
          unsigned short* vb = &((unsigned short*)outp2)[
              (((size_t)bb * NHEADS + hh) * HDIM + dd) * SEQ + (t0 & ~63)];
#pragma unroll
          for (int dlt = 0; dlt < 4; ++dlt)
            vb[((t0 & 15) + dlt) * 4 + jj] = f2bf(vv4[dlt]);
        }
      } else {
#pragma unroll
        for (int r = 0; r < 4; ++r)
          ((float*)outp)[(size_t)(rbase + i * 16 + r) * NDIM + col] = vv4[r];
      }
    }
  }
}

// ---------------------------------------------------------------- flash attention (non-causal)
// Round-15 version: max-free + ones-MFMA softmax, KVBLK=64, 32KB LDS ->
// 4 blocks/CU = 16 waves/CU.
__global__ __launch_bounds__(256, 4) void attn_fwd(const unsigned short* __restrict__ q,
                                                   const unsigned short* __restrict__ k,
                                                   const unsigned short* __restrict__ vt,
                                                   unsigned short* __restrict__ ctx)
{
  __shared__ unsigned short sK[64 * 64];
  __shared__ unsigned short sV[64 * 64];
  __shared__ unsigned short sP[4][32 * 64];

  const int tid = threadIdx.x, w = tid >> 6, l = tid & 63;
  const int lin = blockIdx.y * (SEQ / 128) + blockIdx.x;
  const int W = (lin & 7) * ((BATCH * NHEADS * SEQ / 128) / 8) + (lin >> 3);
  const int bh = W >> 4, b = bh >> 4, hh = bh & 15;
  const int q0 = (W & 15) * 128 + w * 32;
  const size_t base = ((size_t)b * SEQ) * D_MODEL + hh * HDIM;
  const size_t vtbase = (size_t)bh * HDIM * SEQ;

  bf16x8 qf[2][2];
#pragma unroll
  for (int i = 0; i < 2; ++i)
#pragma unroll
    for (int ks = 0; ks < 2; ++ks)
      qf[i][ks] = *reinterpret_cast<const bf16x8*>(
          &q[base + (size_t)(q0 + i * 16 + (l & 15)) * D_MODEL + ks * 32 + (l >> 4) * 8]);

  bf16x8 ones;
#pragma unroll
  for (int e = 0; e < 8; ++e) ones[e] = (__bf16)1.0f;

  f32x4 oacc[2][4] = {};
  f32x4 sumacc[2] = {};

  const int srow8 = l >> 3;
  const int sswz = (l & 7) ^ (srow8 & 7);
  const unsigned short* kg = k + base + (size_t)srow8 * D_MODEL + sswz * 8;
  const unsigned short* vg = vt + vtbase + (size_t)srow8 * SEQ + sswz * 8;

  const int kb0 = l >> 4;
  const int c15 = l & 15;

  for (int kt = 0; kt < SEQ; kt += 64) {
    __syncthreads();
#pragma unroll
    for (int it = 0; it < 2; ++it) {
      const int c = it * 4 + w;
      GLDS(kg + (size_t)(kt + c * 8) * D_MODEL, sK + c * 512);
      GLDS(vg + (size_t)(c * 8) * SEQ + kt, sV + c * 512);
    }
    asm volatile("s_waitcnt vmcnt(0)" ::: "memory");
    __syncthreads();

    // S = Q K^T  (64 keys = 4 j-blocks); scores already in log2 domain
    f32x4 sacc[2][4] = {};
    __builtin_amdgcn_s_setprio(1);
#pragma unroll
    for (int ks = 0; ks < 2; ++ks) {
#pragma unroll
      for (int j = 0; j < 4; ++j) {
        const int row = j * 16 + (l & 15);
        bf16x8 kf = *reinterpret_cast<const bf16x8*>(
            &sK[row * 64 + (((ks * 4 + kb0) ^ (row & 7)) << 3)]);
#pragma unroll
        for (int i = 0; i < 2; ++i) sacc[i][j] = mfma16(qf[i][ks], kf, sacc[i][j]);
      }
    }
    __builtin_amdgcn_s_setprio(0);

    // max-free softmax: p = exp2(s); denominator via ones-MFMA in PV phase.
#pragma unroll
    for (int i = 0; i < 2; ++i) {
#pragma unroll
      for (int r = 0; r < 4; ++r) {
        float p[4];
#pragma unroll
        for (int j = 0; j < 4; ++j) p[j] = __builtin_exp2f(sacc[i][j][r]);
        const int prow = i * 16 + ((l >> 4) << 2) + r;
        u16x4 pk;
        pk[0] = f2bf(p[0]); pk[1] = f2bf(p[1]); pk[2] = f2bf(p[2]); pk[3] = f2bf(p[3]);
        *reinterpret_cast<u16x4*>(
            &sP[w][prow * 64 + ((((c15 >> 1) ^ (prow & 7)) << 3) | ((c15 & 1) << 2))]) = pk;
      }
    }

    // O += P V ; rowsum += P * ones
    __builtin_amdgcn_s_setprio(1);
#pragma unroll
    for (int ks = 0; ks < 2; ++ks) {
      bf16x8 pf[2];
#pragma unroll
      for (int i = 0; i < 2; ++i) {
        const int prw = i * 16 + (l & 15);
        pf[i] = *reinterpret_cast<const bf16x8*>(
            &sP[w][prw * 64 + (((ks * 4 + kb0) ^ (prw & 7)) << 3)]);
      }
#pragma unroll
      for (int j = 0; j < 4; ++j) {
        const int row = j * 16 + (l & 15);
        bf16x8 vf = *reinterpret_cast<const bf16x8*>(
            &sV[row * 64 + (((ks * 4 + kb0) ^ (row & 7)) << 3)]);
#pragma unroll
        for (int i = 0; i < 2; ++i) oacc[i][j] = mfma16(pf[i], vf, oacc[i][j]);
      }
#pragma unroll
      for (int i = 0; i < 2; ++i) sumacc[i] = mfma16(pf[i], ones, sumacc[i]);
    }
    __builtin_amdgcn_s_setprio(0);
  }

#pragma unroll
  for (int i = 0; i < 2; ++i)
#pragma unroll
    for (int r = 0; r < 4; ++r) {
      float inv = 1.f / sumacc[i][r];
      int row = q0 + i * 16 + ((l >> 4) << 2) + r;
#pragma unroll
      for (int j = 0; j < 4; ++j)
        ctx[base + (size_t)row * D_MODEL + j * 16 + (l & 15)] = f2bf(oacc[i][j][r] * inv);
    }
}

// ---------------------------------------------------------------- launch
extern "C" void kernel_launch(void* const* d_in, const int* in_sizes, int n_in,
                              void* d_out, int out_size, void* d_ws, size_t ws_size,
                              hipStream_t stream)
{
  (void)in_sizes; (void)n_in; (void)out_size; (void)ws_size;
  const float* x      = (const float*)d_in[0];
  const float* dyn_q  = (const float*)d_in[1];
  const float* dyn_k  = (const float*)d_in[2];
  const float* dyn_v  = (const float*)d_in[3];
  const float* dyn_f1 = (const float*)d_in[4];
  const float* dyn_f2 = (const float*)d_in[5];
  const float* Wq = (const float*)d_in[6];
  const float* Aq = (const float*)d_in[7];
  const float* Wk = (const float*)d_in[8];
  const float* Ak = (const float*)d_in[9];
  const float* Wv = (const float*)d_in[10];
  const float* Av = (const float*)d_in[11];
  const float* Wo = (const float*)d_in[12];
  const float* W1 = (const float*)d_in[13];
  const float* b1 = (const float*)d_in[14];
  const float* A1 = (const float*)d_in[15];
  const float* W2 = (const float*)d_in[16];
  const float* b2 = (const float*)d_in[17];
  const float* A2 = (const float*)d_in[18];
  const float* g1 = (const float*)d_in[19];
  const float* be1 = (const float*)d_in[20];
  const float* g2 = (const float*)d_in[21];
  const float* be2 = (const float*)d_in[22];

  char* ws = (char*)d_ws;
  size_t o = 0;
  auto take = [&](size_t b) { size_t r = o; o += (b + 255) & ~(size_t)255; return r; };
  const size_t o_wq = take((size_t)D_MODEL * D_MODEL * 2);  // wq,wk,wv contiguous (2MB each)
  const size_t o_wk = take((size_t)D_MODEL * D_MODEL * 2);
  const size_t o_wv = take((size_t)D_MODEL * D_MODEL * 2);
  const size_t o_wo = take((size_t)D_MODEL * D_MODEL * 2);
  const size_t o_w1 = take((size_t)D_FF * D_MODEL * 2);
  const size_t o_w2 = take((size_t)D_FF * D_MODEL * 2);
  const size_t o_h1 = take((size_t)MTOT * D_MODEL * 2);   // later reused as ctx
  const size_t o_q  = take((size_t)MTOT * D_MODEL * 2);   // q,k contiguous; later x2
  const size_t o_k  = take((size_t)MTOT * D_MODEL * 2);
  const size_t o_v  = take((size_t)MTOT * D_MODEL * 2);   // vt; later reused as h2
  const size_t o_u  = take((size_t)MTOT * RANK * 4 * 3);  // u_q,u_k,u_v contiguous
  const size_t o_ff = take((size_t)MTOT * D_FF * 2);

  unsigned short* wq_b = (unsigned short*)(ws + o_wq);
  unsigned short* wk_b = (unsigned short*)(ws + o_wk);
  unsigned short* wv_b = (unsigned short*)(ws + o_wv);
  unsigned short* wo_b = (unsigned short*)(ws + o_wo);
  unsigned short* w1_b = (unsigned short*)(ws + o_w1);
  unsigned short* w2_b = (unsigned short*)(ws + o_w2);
  unsigned short* h1   = (unsigned short*)(ws + o_h1);
  unsigned short* qb   = (unsigned short*)(ws + o_q);
  unsigned short* vtb  = (unsigned short*)(ws + o_v);
  float* u_q  = (float*)(ws + o_u);
  float* u_k  = u_q + (size_t)MTOT * RANK;
  unsigned short* ctx = h1;                    // reuse
  float* x2 = (float*)(ws + o_q);              // reuse q+k (32MB)
  unsigned short* h2 = vtb;                    // reuse
  float* u_f1 = u_q;                           // reuse
  float* u_f2 = u_k;                           // reuse
  unsigned short* ffb = (unsigned short*)(ws + o_ff);

  // 1. weights -> bf16 (single merged launch)
  cvt_bf16_all<<<6144, 256, 0, stream>>>(Wq, Wk, Wv, Wo, W1, W2,
                                         wq_b, wk_b, wv_b, wo_b, w1_b, w2_b);

  // 2. LN1
  ln_fwd<<<MTOT, 256, 0, stream>>>(x, g1, be1, h1);

  // 3. dynamic u for q,k,v (fused, reads h1 once)
  dyn_u_qkv<<<MTOT / 16, 256, 0, stream>>>(h1, dyn_q, dyn_k, dyn_v, u_q);

  // 4. fused QKV projection (BN=256; Q pre-scaled, V pre-transposed+key-permuted)
  gemm_bt<3 * D_MODEL, D_MODEL, 5, 256><<<dim3(3 * D_MODEL / 256, MTOT / 256), 512, 0, stream>>>(
      h1, wq_b, qb, vtb, u_q, Aq, Ak, Av, nullptr, nullptr);

  // 5. attention
  attn_fwd<<<dim3(SEQ / 128, BATCH * NHEADS), 256, 0, stream>>>(
      qb, qb + (size_t)MTOT * D_MODEL, vtb, ctx);

  // 6. Wo + residual -> x2 (fp32), BN=128
  gemm_bt<D_MODEL, D_MODEL, 1, 128><<<dim3(D_MODEL / 128, MTOT / 256), 512, 0, stream>>>(
      ctx, wo_b, x2, nullptr, nullptr, nullptr, nullptr, nullptr, nullptr, x);

  // 7. LN2
  ln_fwd<<<MTOT, 256, 0, stream>>>(x2, g2, be2, h2);

  // 8. u_ff1, FF1 (+bias,+delta,gelu) -> ff bf16, BN=256
  dyn_u<D_MODEL><<<MTOT / 16, 256, 0, stream>>>(h2, dyn_f1, u_f1);
  gemm_bt<D_FF, D_MODEL, 2, 256><<<dim3(D_FF / 256, MTOT / 256), 512, 0, stream>>>(
      h2, w1_b, ffb, nullptr, u_f1, A1, nullptr, nullptr, b1, nullptr);

  // 9. u_ff2, FF2 (+bias,+delta,+resid) -> out fp32, BN=128
  dyn_u<D_FF><<<MTOT / 16, 256, 0, stream>>>(ffb, dyn_f2, u_f2);
  gemm_bt<D_MODEL, D_FF, 3, 128><<<dim3(D_MODEL / 128, MTOT / 256), 512, 0, stream>>>(
      ffb, w2_b, (float*)d_out, nullptr, u_f2, A2, nullptr, nullptr, b2, x2);
}

// Round 18
// 540.260 us; speedup vs baseline: 1.2788x; 1.2158x over previous
//
#include <hip/hip_runtime.h>
#include <math.h>

#define D_MODEL 1024
#define D_FF    4096
#define RANK    8
#define BATCH   4
#define SEQ     2048
#define MTOT    (BATCH*SEQ)
#define NHEADS  16
#define HDIM    64

typedef __attribute__((ext_vector_type(8))) __bf16 bf16x8;
typedef __attribute__((ext_vector_type(4))) float f32x4;
typedef __attribute__((ext_vector_type(8))) unsigned short u16x8;
typedef __attribute__((ext_vector_type(4))) unsigned short u16x4;

// hardware RTNE f32->bf16 (v_cvt on gfx950)
__device__ __forceinline__ unsigned short f2bf(float f) {
  __bf16 h = (__bf16)f;
  return __builtin_bit_cast(unsigned short, h);
}
__device__ __forceinline__ float bf2f(unsigned short h) {
  union { unsigned int u; float f; } v; v.u = ((unsigned int)h) << 16;
  return v.f;
}

__device__ __forceinline__ f32x4 mfma16(bf16x8 a, bf16x8 b, f32x4 c) {
  return __builtin_amdgcn_mfma_f32_16x16x32_bf16(a, b, c, 0, 0, 0);
}

#define GLDS(g, l) __builtin_amdgcn_global_load_lds( \
    (const __attribute__((address_space(1))) void*)(g), \
    (__attribute__((address_space(3))) void*)(l), 16, 0, 0)

// ---------------------------------------------------------------- merged f32 -> bf16 convert
__global__ __launch_bounds__(256) void cvt_bf16_all(
    const float* __restrict__ s0, const float* __restrict__ s1,
    const float* __restrict__ s2, const float* __restrict__ s3,
    const float* __restrict__ s4, const float* __restrict__ s5,
    unsigned short* __restrict__ d0, unsigned short* __restrict__ d1,
    unsigned short* __restrict__ d2, unsigned short* __restrict__ d3,
    unsigned short* __restrict__ d4, unsigned short* __restrict__ d5)
{
  const int b = blockIdx.x;
  const float* src; unsigned short* dst; int base;
  if (b < 512)       { src = s0; dst = d0; base = b; }
  else if (b < 1024) { src = s1; dst = d1; base = b - 512; }
  else if (b < 1536) { src = s2; dst = d2; base = b - 1024; }
  else if (b < 2048) { src = s3; dst = d3; base = b - 1536; }
  else if (b < 4096) { src = s4; dst = d4; base = b - 2048; }
  else               { src = s5; dst = d5; base = b - 4096; }
  const size_t i = (size_t)base * 256 + threadIdx.x;
  const float4 a  = *reinterpret_cast<const float4*>(src + i * 8);
  const float4 c  = *reinterpret_cast<const float4*>(src + i * 8 + 4);
  u16x8 o;
  o[0] = f2bf(a.x); o[1] = f2bf(a.y); o[2] = f2bf(a.z); o[3] = f2bf(a.w);
  o[4] = f2bf(c.x); o[5] = f2bf(c.y); o[6] = f2bf(c.z); o[7] = f2bf(c.w);
  *reinterpret_cast<u16x8*>(dst + i * 8) = o;
}

// ---------------------------------------------------------------- layernorm (fp32 in, bf16 out)
__global__ __launch_bounds__(256) void ln_fwd(const float* __restrict__ x,
                                              const float* __restrict__ g,
                                              const float* __restrict__ be,
                                              unsigned short* __restrict__ out)
{
  const int row = blockIdx.x;
  const int t = threadIdx.x;
  const float* xr = x + (size_t)row * D_MODEL;
  float4 vv = *reinterpret_cast<const float4*>(xr + t * 4);
  float s  = vv.x + vv.y + vv.z + vv.w;
  float s2 = vv.x * vv.x + vv.y * vv.y + vv.z * vv.z + vv.w * vv.w;
#pragma unroll
  for (int mm = 1; mm < 64; mm <<= 1) { s += __shfl_xor(s, mm); s2 += __shfl_xor(s2, mm); }
  __shared__ float red[8];
  const int w = t >> 6, l = t & 63;
  if (l == 0) { red[w] = s; red[4 + w] = s2; }
  __syncthreads();
  s  = red[0] + red[1] + red[2] + red[3];
  s2 = red[4] + red[5] + red[6] + red[7];
  float mean = s * (1.f / D_MODEL);
  float var  = s2 * (1.f / D_MODEL) - mean * mean;
  float rstd = rsqrtf(var + 1e-5f);
  float4 gv = *reinterpret_cast<const float4*>(g  + t * 4);
  float4 bv = *reinterpret_cast<const float4*>(be + t * 4);
  u16x4 o;
  o[0] = f2bf((vv.x - mean) * rstd * gv.x + bv.x);
  o[1] = f2bf((vv.y - mean) * rstd * gv.y + bv.y);
  o[2] = f2bf((vv.z - mean) * rstd * gv.z + bv.z);
  o[3] = f2bf((vv.w - mean) * rstd * gv.w + bv.w);
  *reinterpret_cast<u16x4*>(out + (size_t)row * D_MODEL + t * 4) = o;
}

// ---------------------------------------------------------------- u[m][r] = sum_i h[m][i]*dyn[b][r][i]
// Round-15 scalar version (proven, no spill). The 8-wide variant (r17) with an
// unrolled outer loop hit VGPR=256 + 180MB scratch traffic -- never fully
// unroll a streaming reduction loop.
template<int ILEN>
__global__ __launch_bounds__(256) void dyn_u(const unsigned short* __restrict__ hmat,
                                             const float* __restrict__ dyn,
                                             float* __restrict__ u)
{
  const int tid = threadIdx.x, w = tid >> 6, l = tid & 63;
  const int m0 = blockIdx.x * 16 + w * 4;
  const int b = m0 / SEQ;
  const float* dynb = dyn + (size_t)b * RANK * ILEN;
  float acc[4][RANK] = {};
  for (int s = 0; s < ILEN / 64; ++s) {
    const int i = l + s * 64;
    float hv[4];
#pragma unroll
    for (int rr = 0; rr < 4; ++rr) hv[rr] = bf2f(hmat[(size_t)(m0 + rr) * ILEN + i]);
#pragma unroll
    for (int r = 0; r < RANK; ++r) {
      float d = dynb[(size_t)r * ILEN + i];
#pragma unroll
      for (int rr = 0; rr < 4; ++rr) acc[rr][r] += hv[rr] * d;
    }
  }
#pragma unroll
  for (int rr = 0; rr < 4; ++rr)
#pragma unroll
    for (int r = 0; r < RANK; ++r) {
      float a = acc[rr][r];
#pragma unroll
      for (int mm = 1; mm < 64; mm <<= 1) a += __shfl_xor(a, mm);
      if (l == 0) u[(size_t)(m0 + rr) * RANK + r] = a;
    }
}

// fused q/k/v u-computation: reads h once, produces u[3][MTOT][RANK]
__global__ __launch_bounds__(256) void dyn_u_qkv(const unsigned short* __restrict__ hmat,
                                                 const float* __restrict__ dq,
                                                 const float* __restrict__ dk,
                                                 const float* __restrict__ dv,
                                                 float* __restrict__ u)
{
  const int tid = threadIdx.x, w = tid >> 6, l = tid & 63;
  const int m0 = blockIdx.x * 16 + w * 4;
  const int b = m0 / SEQ;
  const float* db0 = dq + (size_t)b * RANK * D_MODEL;
  const float* db1 = dk + (size_t)b * RANK * D_MODEL;
  const float* db2 = dv + (size_t)b * RANK * D_MODEL;
  float acc[4][3 * RANK] = {};
  for (int s = 0; s < D_MODEL / 64; ++s) {
    const int i = l + s * 64;
    float hv[4];
#pragma unroll
    for (int rr = 0; rr < 4; ++rr) hv[rr] = bf2f(hmat[(size_t)(m0 + rr) * D_MODEL + i]);
#pragma unroll
    for (int r = 0; r < RANK; ++r) {
      float d0 = db0[(size_t)r * D_MODEL + i];
      float d1 = db1[(size_t)r * D_MODEL + i];
      float d2 = db2[(size_t)r * D_MODEL + i];
#pragma unroll
      for (int rr = 0; rr < 4; ++rr) {
        acc[rr][r] += hv[rr] * d0;
        acc[rr][RANK + r] += hv[rr] * d1;
        acc[rr][2 * RANK + r] += hv[rr] * d2;
      }
    }
  }
#pragma unroll
  for (int g = 0; g < 3; ++g)
#pragma unroll
    for (int rr = 0; rr < 4; ++rr)
#pragma unroll
      for (int r = 0; r < RANK; ++r) {
        float a = acc[rr][g * RANK + r];
#pragma unroll
        for (int mm = 1; mm < 64; mm <<= 1) a += __shfl_xor(a, mm);
        if (l == 0) u[((size_t)g * MTOT + m0 + rr) * RANK + r] = a;
      }
}

// ---------------------------------------------------------------- GEMM  C[m,n] = sum_k A[m,k]*B[n,k] (+epilogue)
// Round-15 proven config (exact): BM=256, BN templated (128/256), BK=64,
// 8 waves, 2-buffer LDS, prefetch-before-compute. erff GELU kept: the inline
// fast-gelu (r16) triggered epilogue software-pipelining -> spill (+115MB HBM).
// MODE 1: +resid(fp32), fp32 out (Wo)
// MODE 2: +dyn delta +bias, gelu, bf16 out (FF1)
// MODE 3: +dyn delta +bias +resid, fp32 out (FF2)
// MODE 5: fused QKV -> {Q (pre-scaled), K, V transposed+key-permuted to vt}
template<int NDIM, int KDIM, int MODE, int BN>
__global__ __launch_bounds__(512, (BN == 256) ? 1 : 2)
void gemm_bt(const unsigned short* __restrict__ A,
             const unsigned short* __restrict__ B,
             void* __restrict__ outp,
             void* __restrict__ outp2,
             const float* __restrict__ uvec,
             const float* __restrict__ Ad0,
             const float* __restrict__ Ad1,
             const float* __restrict__ Ad2,
             const float* __restrict__ bias,
             const float* __restrict__ resid)
{
  constexpr bool HAS_DYN = (MODE == 2 || MODE == 3 || MODE == 5);
  constexpr int WN = BN / 64;       // waves along N
  constexpr int WM = 8 / WN;        // waves along M
  constexpr int MSPAN = 256 / WM;   // per-wave M extent
  constexpr int NI = MSPAN / 16;    // M-fragments per wave
  __shared__ unsigned short sAB[2][(256 + BN) * 64];
  const int tid = threadIdx.x;
  const int w = tid >> 6, l = tid & 63;

  constexpr int NBX = NDIM / BN;
  constexpr int NWG = NBX * (MTOT / 256);
  const int bid = blockIdx.y * NBX + blockIdx.x;
  const int sbid = (bid & 7) * (NWG / 8) + (bid >> 3);
  const int tm = (sbid / NBX) * 256, tn = (sbid % NBX) * BN;
  const int wm = w / WN, wn = w % WN;

  f32x4 acc[NI][4] = {};

  const int srow = l >> 3;
  const int sc8 = (l & 7) ^ (srow & 7);
  const unsigned short* Ag = A + (size_t)(tm + srow) * KDIM + sc8 * 8;
  const unsigned short* Bg = B + (size_t)(tn + srow) * KDIM + sc8 * 8;

  const int arow = wm * MSPAN + (l & 15);
  const int bcol = wn * 64 + (l & 15);
  const int kb0 = l >> 4;
  const int swz = l & 7;

  constexpr int NT = KDIM / 64;

  auto stage = [&](int buf, int kt) {
    unsigned short* bA = &sAB[buf][0];
    unsigned short* bB = &sAB[buf][256 * 64];
#pragma unroll
    for (int it = 0; it < 4; ++it) {
      const int st = w * 4 + it;
      GLDS(Ag + (size_t)(st * 8) * KDIM + kt, bA + st * 512);
    }
#pragma unroll
    for (int it = 0; it < WN; ++it) {
      const int st = w * WN + it;
      GLDS(Bg + (size_t)(st * 8) * KDIM + kt, bB + st * 512);
    }
  };

  stage(0, 0);
  asm volatile("s_waitcnt vmcnt(0)" ::: "memory");
  __syncthreads();

  int cur = 0;
  for (int t = 0; t < NT; ++t) {
    if (t + 1 < NT) stage(cur ^ 1, (t + 1) * 64);

    const unsigned short* sA_ = &sAB[cur][0];
    const unsigned short* sB_ = &sAB[cur][256 * 64];
#pragma unroll
    for (int kk = 0; kk < 2; ++kk) {
      bf16x8 af[NI], bfv[4];
      const int kphys = ((kk * 4 + kb0) ^ swz) << 3;
#pragma unroll
      for (int i = 0; i < NI; ++i)
        af[i] = *reinterpret_cast<const bf16x8*>(&sA_[(arow + i * 16) * 64 + kphys]);
#pragma unroll
      for (int j = 0; j < 4; ++j)
        bfv[j] = *reinterpret_cast<const bf16x8*>(&sB_[(bcol + j * 16) * 64 + kphys]);
#pragma unroll
      for (int i = 0; i < NI; ++i)
#pragma unroll
        for (int j = 0; j < 4; ++j)
          acc[i][j] = mfma16(af[i], bfv[j], acc[i][j]);
    }
    __syncthreads();
    cur ^= 1;
  }

  const int rbase = tm + wm * MSPAN + ((l >> 4) << 2);
  const int cbase = tn + wn * 64 + (l & 15);

  const int seg = tn >> 10;   // MODE 5: tiles never cross a 1024 segment
  const float* Ad = Ad0;
  const float* uv = uvec;
  if constexpr (MODE == 5) {
    Ad = (seg == 0) ? Ad0 : (seg == 1) ? Ad1 : Ad2;
    uv = uvec + (size_t)seg * ((size_t)MTOT * RANK);
  }

#pragma unroll
  for (int i = 0; i < NI; ++i) {
    float uu[4][8];
    if constexpr (HAS_DYN) {
#pragma unroll
      for (int r = 0; r < 4; ++r) {
        const float* up = uv + (size_t)(rbase + i * 16 + r) * RANK;
#pragma unroll
        for (int p = 0; p < 8; ++p) uu[r][p] = up[p];
      }
    }
#pragma unroll
    for (int j = 0; j < 4; ++j) {
      const int col = cbase + j * 16;
      float ad[8];
      if constexpr (HAS_DYN) {
#pragma unroll
        for (int p = 0; p < 8; ++p) ad[p] = Ad[(size_t)col * RANK + p];
      }
      float vv4[4];
#pragma unroll
      for (int r = 0; r < 4; ++r) {
        const int row = rbase + i * 16 + r;
        float v = acc[i][j][r];
        if constexpr (HAS_DYN) {
#pragma unroll
          for (int p = 0; p < 8; ++p) v += uu[r][p] * ad[p];
        }
        if constexpr (MODE == 2) {
          v += bias[col];
          v = 0.5f * v * (1.f + erff(v * 0.70710678118654752f));
        }
        if constexpr (MODE == 1) {
          v += resid[(size_t)row * NDIM + col];
        }
        if constexpr (MODE == 3) {
          v += bias[col] + resid[(size_t)row * NDIM + col];
        }
        if constexpr (MODE == 5) {
          if (seg == 0) v *= 0.18033688011112042f;  // 0.125 * log2(e)
        }
        vv4[r] = v;
      }
      if constexpr (MODE == 2) {
#pragma unroll
        for (int r = 0; r < 4; ++r)
          ((unsigned short*)outp)[(size_t)(rbase + i * 16 + r) * NDIM + col] = f2bf(vv4[r]);
      } else if constexpr (MODE == 5) {
        const int cl = col & 1023;
        if (seg < 2) {
#pragma unroll
          for (int r = 0; r < 4; ++r)
            ((unsigned short*)outp)[((size_t)seg * MTOT + rbase + i * 16 + r) * D_MODEL + cl] =
                f2bf(vv4[r]);
        } else {
          // vt[b][h][d][t'] key-permuted: token k -> slot (k&15)*4 + ((k>>4)&3)
          const int row0 = rbase + i * 16;
          const int bb = row0 >> 11, t0 = row0 & (SEQ - 1);
          const int hh = cl >> 6, dd = cl & 63;
          const int jj = (t0 >> 4) & 3;
          unsigned short* vb = &((unsigned short*)outp2)[
              (((size_t)bb * NHEADS + hh) * HDIM + dd) * SEQ + (t0 & ~63)];
#pragma unroll
          for (int dlt = 0; dlt < 4; ++dlt)
            vb[((t0 & 15) + dlt) * 4 + jj] = f2bf(vv4[dlt]);
        }
      } else {
#pragma unroll
        for (int r = 0; r < 4; ++r)
          ((float*)outp)[(size_t)(rbase + i * 16 + r) * NDIM + col] = vv4[r];
      }
    }
  }
}

// ---------------------------------------------------------------- flash attention (non-causal)
// Round-15 version: max-free + ones-MFMA softmax, KVBLK=64, 32KB LDS ->
// 4 blocks/CU = 16 waves/CU.
__global__ __launch_bounds__(256, 4) void attn_fwd(const unsigned short* __restrict__ q,
                                                   const unsigned short* __restrict__ k,
                                                   const unsigned short* __restrict__ vt,
                                                   unsigned short* __restrict__ ctx)
{
  __shared__ unsigned short sK[64 * 64];
  __shared__ unsigned short sV[64 * 64];
  __shared__ unsigned short sP[4][32 * 64];

  const int tid = threadIdx.x, w = tid >> 6, l = tid & 63;
  const int lin = blockIdx.y * (SEQ / 128) + blockIdx.x;
  const int W = (lin & 7) * ((BATCH * NHEADS * SEQ / 128) / 8) + (lin >> 3);
  const int bh = W >> 4, b = bh >> 4, hh = bh & 15;
  const int q0 = (W & 15) * 128 + w * 32;
  const size_t base = ((size_t)b * SEQ) * D_MODEL + hh * HDIM;
  const size_t vtbase = (size_t)bh * HDIM * SEQ;

  bf16x8 qf[2][2];
#pragma unroll
  for (int i = 0; i < 2; ++i)
#pragma unroll
    for (int ks = 0; ks < 2; ++ks)
      qf[i][ks] = *reinterpret_cast<const bf16x8*>(
          &q[base + (size_t)(q0 + i * 16 + (l & 15)) * D_MODEL + ks * 32 + (l >> 4) * 8]);

  bf16x8 ones;
#pragma unroll
  for (int e = 0; e < 8; ++e) ones[e] = (__bf16)1.0f;

  f32x4 oacc[2][4] = {};
  f32x4 sumacc[2] = {};

  const int srow8 = l >> 3;
  const int sswz = (l & 7) ^ (srow8 & 7);
  const unsigned short* kg = k + base + (size_t)srow8 * D_MODEL + sswz * 8;
  const unsigned short* vg = vt + vtbase + (size_t)srow8 * SEQ + sswz * 8;

  const int kb0 = l >> 4;
  const int c15 = l & 15;

  for (int kt = 0; kt < SEQ; kt += 64) {
    __syncthreads();
#pragma unroll
    for (int it = 0; it < 2; ++it) {
      const int c = it * 4 + w;
      GLDS(kg + (size_t)(kt + c * 8) * D_MODEL, sK + c * 512);
      GLDS(vg + (size_t)(c * 8) * SEQ + kt, sV + c * 512);
    }
    asm volatile("s_waitcnt vmcnt(0)" ::: "memory");
    __syncthreads();

    // S = Q K^T  (64 keys = 4 j-blocks); scores already in log2 domain
    f32x4 sacc[2][4] = {};
    __builtin_amdgcn_s_setprio(1);
#pragma unroll
    for (int ks = 0; ks < 2; ++ks) {
#pragma unroll
      for (int j = 0; j < 4; ++j) {
        const int row = j * 16 + (l & 15);
        bf16x8 kf = *reinterpret_cast<const bf16x8*>(
            &sK[row * 64 + (((ks * 4 + kb0) ^ (row & 7)) << 3)]);
#pragma unroll
        for (int i = 0; i < 2; ++i) sacc[i][j] = mfma16(qf[i][ks], kf, sacc[i][j]);
      }
    }
    __builtin_amdgcn_s_setprio(0);

    // max-free softmax: p = exp2(s); denominator via ones-MFMA in PV phase.
#pragma unroll
    for (int i = 0; i < 2; ++i) {
#pragma unroll
      for (int r = 0; r < 4; ++r) {
        float p[4];
#pragma unroll
        for (int j = 0; j < 4; ++j) p[j] = __builtin_exp2f(sacc[i][j][r]);
        const int prow = i * 16 + ((l >> 4) << 2) + r;
        u16x4 pk;
        pk[0] = f2bf(p[0]); pk[1] = f2bf(p[1]); pk[2] = f2bf(p[2]); pk[3] = f2bf(p[3]);
        *reinterpret_cast<u16x4*>(
            &sP[w][prow * 64 + ((((c15 >> 1) ^ (prow & 7)) << 3) | ((c15 & 1) << 2))]) = pk;
      }
    }

    // O += P V ; rowsum += P * ones
    __builtin_amdgcn_s_setprio(1);
#pragma unroll
    for (int ks = 0; ks < 2; ++ks) {
      bf16x8 pf[2];
#pragma unroll
      for (int i = 0; i < 2; ++i) {
        const int prw = i * 16 + (l & 15);
        pf[i] = *reinterpret_cast<const bf16x8*>(
            &sP[w][prw * 64 + (((ks * 4 + kb0) ^ (prw & 7)) << 3)]);
      }
#pragma unroll
      for (int j = 0; j < 4; ++j) {
        const int row = j * 16 + (l & 15);
        bf16x8 vf = *reinterpret_cast<const bf16x8*>(
            &sV[row * 64 + (((ks * 4 + kb0) ^ (row & 7)) << 3)]);
#pragma unroll
        for (int i = 0; i < 2; ++i) oacc[i][j] = mfma16(pf[i], vf, oacc[i][j]);
      }
#pragma unroll
      for (int i = 0; i < 2; ++i) sumacc[i] = mfma16(pf[i], ones, sumacc[i]);
    }
    __builtin_amdgcn_s_setprio(0);
  }

#pragma unroll
  for (int i = 0; i < 2; ++i)
#pragma unroll
    for (int r = 0; r < 4; ++r) {
      float inv = 1.f / sumacc[i][r];
      int row = q0 + i * 16 + ((l >> 4) << 2) + r;
#pragma unroll
      for (int j = 0; j < 4; ++j)
        ctx[base + (size_t)row * D_MODEL + j * 16 + (l & 15)] = f2bf(oacc[i][j][r] * inv);
    }
}

// ---------------------------------------------------------------- launch
extern "C" void kernel_launch(void* const* d_in, const int* in_sizes, int n_in,
                              void* d_out, int out_size, void* d_ws, size_t ws_size,
                              hipStream_t stream)
{
  (void)in_sizes; (void)n_in; (void)out_size; (void)ws_size;
  const float* x      = (const float*)d_in[0];
  const float* dyn_q  = (const float*)d_in[1];
  const float* dyn_k  = (const float*)d_in[2];
  const float* dyn_v  = (const float*)d_in[3];
  const float* dyn_f1 = (const float*)d_in[4];
  const float* dyn_f2 = (const float*)d_in[5];
  const float* Wq = (const float*)d_in[6];
  const float* Aq = (const float*)d_in[7];
  const float* Wk = (const float*)d_in[8];
  const float* Ak = (const float*)d_in[9];
  const float* Wv = (const float*)d_in[10];
  const float* Av = (const float*)d_in[11];
  const float* Wo = (const float*)d_in[12];
  const float* W1 = (const float*)d_in[13];
  const float* b1 = (const float*)d_in[14];
  const float* A1 = (const float*)d_in[15];
  const float* W2 = (const float*)d_in[16];
  const float* b2 = (const float*)d_in[17];
  const float* A2 = (const float*)d_in[18];
  const float* g1 = (const float*)d_in[19];
  const float* be1 = (const float*)d_in[20];
  const float* g2 = (const float*)d_in[21];
  const float* be2 = (const float*)d_in[22];

  char* ws = (char*)d_ws;
  size_t o = 0;
  auto take = [&](size_t b) { size_t r = o; o += (b + 255) & ~(size_t)255; return r; };
  const size_t o_wq = take((size_t)D_MODEL * D_MODEL * 2);  // wq,wk,wv contiguous (2MB each)
  const size_t o_wk = take((size_t)D_MODEL * D_MODEL * 2);
  const size_t o_wv = take((size_t)D_MODEL * D_MODEL * 2);
  const size_t o_wo = take((size_t)D_MODEL * D_MODEL * 2);
  const size_t o_w1 = take((size_t)D_FF * D_MODEL * 2);
  const size_t o_w2 = take((size_t)D_FF * D_MODEL * 2);
  const size_t o_h1 = take((size_t)MTOT * D_MODEL * 2);   // later reused as ctx
  const size_t o_q  = take((size_t)MTOT * D_MODEL * 2);   // q,k contiguous; later x2
  const size_t o_k  = take((size_t)MTOT * D_MODEL * 2);
  const size_t o_v  = take((size_t)MTOT * D_MODEL * 2);   // vt; later reused as h2
  const size_t o_u  = take((size_t)MTOT * RANK * 4 * 3);  // u_q,u_k,u_v contiguous
  const size_t o_ff = take((size_t)MTOT * D_FF * 2);

  unsigned short* wq_b = (unsigned short*)(ws + o_wq);
  unsigned short* wk_b = (unsigned short*)(ws + o_wk);
  unsigned short* wv_b = (unsigned short*)(ws + o_wv);
  unsigned short* wo_b = (unsigned short*)(ws + o_wo);
  unsigned short* w1_b = (unsigned short*)(ws + o_w1);
  unsigned short* w2_b = (unsigned short*)(ws + o_w2);
  unsigned short* h1   = (unsigned short*)(ws + o_h1);
  unsigned short* qb   = (unsigned short*)(ws + o_q);
  unsigned short* vtb  = (unsigned short*)(ws + o_v);
  float* u_q  = (float*)(ws + o_u);
  float* u_k  = u_q + (size_t)MTOT * RANK;
  unsigned short* ctx = h1;                    // reuse
  float* x2 = (float*)(ws + o_q);              // reuse q+k (32MB)
  unsigned short* h2 = vtb;                    // reuse
  float* u_f1 = u_q;                           // reuse
  float* u_f2 = u_k;                           // reuse
  unsigned short* ffb = (unsigned short*)(ws + o_ff);

  // 1. weights -> bf16 (single merged launch)
  cvt_bf16_all<<<6144, 256, 0, stream>>>(Wq, Wk, Wv, Wo, W1, W2,
                                         wq_b, wk_b, wv_b, wo_b, w1_b, w2_b);

  // 2. LN1
  ln_fwd<<<MTOT, 256, 0, stream>>>(x, g1, be1, h1);

  // 3. dynamic u for q,k,v (fused, reads h1 once)
  dyn_u_qkv<<<MTOT / 16, 256, 0, stream>>>(h1, dyn_q, dyn_k, dyn_v, u_q);

  // 4. fused QKV projection (BN=256; Q pre-scaled, V pre-transposed+key-permuted)
  gemm_bt<3 * D_MODEL, D_MODEL, 5, 256><<<dim3(3 * D_MODEL / 256, MTOT / 256), 512, 0, stream>>>(
      h1, wq_b, qb, vtb, u_q, Aq, Ak, Av, nullptr, nullptr);

  // 5. attention
  attn_fwd<<<dim3(SEQ / 128, BATCH * NHEADS), 256, 0, stream>>>(
      qb, qb + (size_t)MTOT * D_MODEL, vtb, ctx);

  // 6. Wo + residual -> x2 (fp32), BN=128
  gemm_bt<D_MODEL, D_MODEL, 1, 128><<<dim3(D_MODEL / 128, MTOT / 256), 512, 0, stream>>>(
      ctx, wo_b, x2, nullptr, nullptr, nullptr, nullptr, nullptr, nullptr, x);

  // 7. LN2
  ln_fwd<<<MTOT, 256, 0, stream>>>(x2, g2, be2, h2);

  // 8. u_ff1, FF1 (+bias,+delta,gelu) -> ff bf16, BN=256
  dyn_u<D_MODEL><<<MTOT / 16, 256, 0, stream>>>(h2, dyn_f1, u_f1);
  gemm_bt<D_FF, D_MODEL, 2, 256><<<dim3(D_FF / 256, MTOT / 256), 512, 0, stream>>>(
      h2, w1_b, ffb, nullptr, u_f1, A1, nullptr, nullptr, b1, nullptr);

  // 9. u_ff2, FF2 (+bias,+delta,+resid) -> out fp32, BN=128
  dyn_u<D_FF><<<MTOT / 16, 256, 0, stream>>>(ffb, dyn_f2, u_f2);
  gemm_bt<D_MODEL, D_FF, 3, 128><<<dim3(D_MODEL / 128, MTOT / 256), 512, 0, stream>>>(
      ffb, w2_b, (float*)d_out, nullptr, u_f2, A2, nullptr, nullptr, b2, x2);
}

// Round 19
// 502.956 us; speedup vs baseline: 1.3737x; 1.0742x over previous
//
#include <hip/hip_runtime.h>
#include <math.h>

#define D_MODEL 1024
#define D_FF    4096
#define RANK    8
#define BATCH   4
#define SEQ     2048
#define MTOT    (BATCH*SEQ)
#define NHEADS  16
#define HDIM    64

typedef __attribute__((ext_vector_type(8))) __bf16 bf16x8;
typedef __attribute__((ext_vector_type(4))) float f32x4;
typedef __attribute__((ext_vector_type(8))) unsigned short u16x8;
typedef __attribute__((ext_vector_type(4))) unsigned short u16x4;

// hardware RTNE f32->bf16 (v_cvt on gfx950)
__device__ __forceinline__ unsigned short f2bf(float f) {
  __bf16 h = (__bf16)f;
  return __builtin_bit_cast(unsigned short, h);
}
__device__ __forceinline__ float bf2f(unsigned short h) {
  union { unsigned int u; float f; } v; v.u = ((unsigned int)h) << 16;
  return v.f;
}

__device__ __forceinline__ f32x4 mfma16(bf16x8 a, bf16x8 b, f32x4 c) {
  return __builtin_amdgcn_mfma_f32_16x16x32_bf16(a, b, c, 0, 0, 0);
}

#define GLDS(g, l) __builtin_amdgcn_global_load_lds( \
    (const __attribute__((address_space(1))) void*)(g), \
    (__attribute__((address_space(3))) void*)(l), 16, 0, 0)

// ---------------------------------------------------------------- merged f32 -> bf16 convert
__global__ __launch_bounds__(256) void cvt_bf16_all(
    const float* __restrict__ s0, const float* __restrict__ s1,
    const float* __restrict__ s2, const float* __restrict__ s3,
    const float* __restrict__ s4, const float* __restrict__ s5,
    unsigned short* __restrict__ d0, unsigned short* __restrict__ d1,
    unsigned short* __restrict__ d2, unsigned short* __restrict__ d3,
    unsigned short* __restrict__ d4, unsigned short* __restrict__ d5)
{
  const int b = blockIdx.x;
  const float* src; unsigned short* dst; int base;
  if (b < 512)       { src = s0; dst = d0; base = b; }
  else if (b < 1024) { src = s1; dst = d1; base = b - 512; }
  else if (b < 1536) { src = s2; dst = d2; base = b - 1024; }
  else if (b < 2048) { src = s3; dst = d3; base = b - 1536; }
  else if (b < 4096) { src = s4; dst = d4; base = b - 2048; }
  else               { src = s5; dst = d5; base = b - 4096; }
  const size_t i = (size_t)base * 256 + threadIdx.x;
  const float4 a  = *reinterpret_cast<const float4*>(src + i * 8);
  const float4 c  = *reinterpret_cast<const float4*>(src + i * 8 + 4);
  u16x8 o;
  o[0] = f2bf(a.x); o[1] = f2bf(a.y); o[2] = f2bf(a.z); o[3] = f2bf(a.w);
  o[4] = f2bf(c.x); o[5] = f2bf(c.y); o[6] = f2bf(c.z); o[7] = f2bf(c.w);
  *reinterpret_cast<u16x8*>(dst + i * 8) = o;
}

// ---------------------------------------------------------------- Ad -> padded bf16 ext tables
// eqkv[3072][64] (Aq|Ak|Av), e1[4096][64] (A1), e2[1024][64] (A2); col p<8 real, else 0.
__global__ __launch_bounds__(256) void ad_ext(
    const float* __restrict__ Aq, const float* __restrict__ Ak,
    const float* __restrict__ Av, const float* __restrict__ A1,
    const float* __restrict__ A2,
    unsigned short* __restrict__ eqkv, unsigned short* __restrict__ e1,
    unsigned short* __restrict__ e2)
{
  const int n = blockIdx.x * 256 + threadIdx.x;   // 8192 rows total
  const float* src; unsigned short* dst;
  if (n < 3072) {
    src = (n < 1024) ? (Aq + (size_t)n * 8)
        : (n < 2048) ? (Ak + (size_t)(n - 1024) * 8)
                     : (Av + (size_t)(n - 2048) * 8);
    dst = eqkv + (size_t)n * 64;
  } else if (n < 7168) {
    src = A1 + (size_t)(n - 3072) * 8; dst = e1 + (size_t)(n - 3072) * 64;
  } else {
    src = A2 + (size_t)(n - 7168) * 8; dst = e2 + (size_t)(n - 7168) * 64;
  }
  u16x8 v;
#pragma unroll
  for (int p = 0; p < 8; ++p) v[p] = f2bf(src[p]);
  *reinterpret_cast<u16x8*>(dst) = v;
  u16x8 z = {};
#pragma unroll
  for (int c = 1; c < 8; ++c) *reinterpret_cast<u16x8*>(dst + c * 8) = z;
}

// ---------------------------------------------------------------- layernorm (fp32 in, bf16 out)
__global__ __launch_bounds__(256) void ln_fwd(const float* __restrict__ x,
                                              const float* __restrict__ g,
                                              const float* __restrict__ be,
                                              unsigned short* __restrict__ out)
{
  const int row = blockIdx.x;
  const int t = threadIdx.x;
  const float* xr = x + (size_t)row * D_MODEL;
  float4 vv = *reinterpret_cast<const float4*>(xr + t * 4);
  float s  = vv.x + vv.y + vv.z + vv.w;
  float s2 = vv.x * vv.x + vv.y * vv.y + vv.z * vv.z + vv.w * vv.w;
#pragma unroll
  for (int mm = 1; mm < 64; mm <<= 1) { s += __shfl_xor(s, mm); s2 += __shfl_xor(s2, mm); }
  __shared__ float red[8];
  const int w = t >> 6, l = t & 63;
  if (l == 0) { red[w] = s; red[4 + w] = s2; }
  __syncthreads();
  s  = red[0] + red[1] + red[2] + red[3];
  s2 = red[4] + red[5] + red[6] + red[7];
  float mean = s * (1.f / D_MODEL);
  float var  = s2 * (1.f / D_MODEL) - mean * mean;
  float rstd = rsqrtf(var + 1e-5f);
  float4 gv = *reinterpret_cast<const float4*>(g  + t * 4);
  float4 bv = *reinterpret_cast<const float4*>(be + t * 4);
  u16x4 o;
  o[0] = f2bf((vv.x - mean) * rstd * gv.x + bv.x);
  o[1] = f2bf((vv.y - mean) * rstd * gv.y + bv.y);
  o[2] = f2bf((vv.z - mean) * rstd * gv.z + bv.z);
  o[3] = f2bf((vv.w - mean) * rstd * gv.w + bv.w);
  *reinterpret_cast<u16x4*>(out + (size_t)row * D_MODEL + t * 4) = o;
}

// ---------------------------------------------------------------- u-ext: uext[m][64] bf16
// (cols 0-7 = sum_i h[m][i]*dyn[b][r][i], cols 8-63 = 0). Butterfly all-reduce
// leaves the sum in every lane; lane l stores col l.
template<int ILEN>
__global__ __launch_bounds__(256) void dyn_u(const unsigned short* __restrict__ hmat,
                                             const float* __restrict__ dyn,
                                             unsigned short* __restrict__ uext)
{
  const int tid = threadIdx.x, w = tid >> 6, l = tid & 63;
  const int m0 = blockIdx.x * 16 + w * 4;
  const int b = m0 / SEQ;
  const float* dynb = dyn + (size_t)b * RANK * ILEN;
  float acc[4][RANK] = {};
  for (int s = 0; s < ILEN / 64; ++s) {
    const int i = l + s * 64;
    float hv[4];
#pragma unroll
    for (int rr = 0; rr < 4; ++rr) hv[rr] = bf2f(hmat[(size_t)(m0 + rr) * ILEN + i]);
#pragma unroll
    for (int r = 0; r < RANK; ++r) {
      float d = dynb[(size_t)r * ILEN + i];
#pragma unroll
      for (int rr = 0; rr < 4; ++rr) acc[rr][r] += hv[rr] * d;
    }
  }
#pragma unroll
  for (int rr = 0; rr < 4; ++rr) {
    float red[RANK];
#pragma unroll
    for (int r = 0; r < RANK; ++r) {
      float a = acc[rr][r];
#pragma unroll
      for (int mm = 1; mm < 64; mm <<= 1) a += __shfl_xor(a, mm);
      red[r] = a;
    }
    const float mine =
        (l == 0) ? red[0] : (l == 1) ? red[1] : (l == 2) ? red[2] : (l == 3) ? red[3] :
        (l == 4) ? red[4] : (l == 5) ? red[5] : (l == 6) ? red[6] : (l == 7) ? red[7] : 0.f;
    uext[(size_t)(m0 + rr) * 64 + l] = f2bf(mine);
  }
}

// fused q/k/v u-ext: reads h once, produces uext[3][MTOT][64]
__global__ __launch_bounds__(256) void dyn_u_qkv(const unsigned short* __restrict__ hmat,
                                                 const float* __restrict__ dq,
                                                 const float* __restrict__ dk,
                                                 const float* __restrict__ dv,
                                                 unsigned short* __restrict__ uext)
{
  const int tid = threadIdx.x, w = tid >> 6, l = tid & 63;
  const int m0 = blockIdx.x * 16 + w * 4;
  const int b = m0 / SEQ;
  const float* db0 = dq + (size_t)b * RANK * D_MODEL;
  const float* db1 = dk + (size_t)b * RANK * D_MODEL;
  const float* db2 = dv + (size_t)b * RANK * D_MODEL;
  float acc[4][3 * RANK] = {};
  for (int s = 0; s < D_MODEL / 64; ++s) {
    const int i = l + s * 64;
    float hv[4];
#pragma unroll
    for (int rr = 0; rr < 4; ++rr) hv[rr] = bf2f(hmat[(size_t)(m0 + rr) * D_MODEL + i]);
#pragma unroll
    for (int r = 0; r < RANK; ++r) {
      float d0 = db0[(size_t)r * D_MODEL + i];
      float d1 = db1[(size_t)r * D_MODEL + i];
      float d2 = db2[(size_t)r * D_MODEL + i];
#pragma unroll
      for (int rr = 0; rr < 4; ++rr) {
        acc[rr][r] += hv[rr] * d0;
        acc[rr][RANK + r] += hv[rr] * d1;
        acc[rr][2 * RANK + r] += hv[rr] * d2;
      }
    }
  }
#pragma unroll
  for (int g = 0; g < 3; ++g)
#pragma unroll
    for (int rr = 0; rr < 4; ++rr) {
      float red[RANK];
#pragma unroll
      for (int r = 0; r < RANK; ++r) {
        float a = acc[rr][g * RANK + r];
#pragma unroll
        for (int mm = 1; mm < 64; mm <<= 1) a += __shfl_xor(a, mm);
        red[r] = a;
      }
      const float mine =
          (l == 0) ? red[0] : (l == 1) ? red[1] : (l == 2) ? red[2] : (l == 3) ? red[3] :
          (l == 4) ? red[4] : (l == 5) ? red[5] : (l == 6) ? red[6] : (l == 7) ? red[7] : 0.f;
      uext[((size_t)g * MTOT + m0 + rr) * 64 + l] = f2bf(mine);
    }
}

// ---------------------------------------------------------------- GEMM  C[m,n] = sum_k A[m,k]*B[n,k] (+epilogue)
// Round-15 loop + K-EXTENSION for the rank-8 dyn delta: C = [A|u]-[B|Ad]^T,
// one extra 64-wide K-tile staged from padded bf16 ext buffers (8 real cols +
// 56 zeros). Removes the entire per-element delta epilogue (8 FMA + scalar
// u/Ad loads per output). erff GELU kept (fast-gelu spilled in r16).
// MODE 1: +resid(fp32), fp32 out (Wo) [no ext]
// MODE 2: +bias, gelu, bf16 out (FF1) [ext]
// MODE 3: +bias +resid, fp32 out (FF2) [ext]
// MODE 5: fused QKV -> {Q (pre-scaled), K, V transposed+key-permuted} [ext, per-seg u]
template<int NDIM, int KDIM, int MODE, int BN>
__global__ __launch_bounds__(512, (BN == 256) ? 1 : 2)
void gemm_bt(const unsigned short* __restrict__ A,
             const unsigned short* __restrict__ B,
             void* __restrict__ outp,
             void* __restrict__ outp2,
             const unsigned short* __restrict__ Aext,
             const unsigned short* __restrict__ Bext,
             const float* __restrict__ bias,
             const float* __restrict__ resid)
{
  constexpr bool HAS_EXT = (MODE == 2 || MODE == 3 || MODE == 5);
  constexpr int WN = BN / 64;       // waves along N
  constexpr int WM = 8 / WN;        // waves along M
  constexpr int MSPAN = 256 / WM;   // per-wave M extent
  constexpr int NI = MSPAN / 16;    // M-fragments per wave
  __shared__ unsigned short sAB[2][(256 + BN) * 64];
  const int tid = threadIdx.x;
  const int w = tid >> 6, l = tid & 63;

  constexpr int NBX = NDIM / BN;
  constexpr int NWG = NBX * (MTOT / 256);
  const int bid = blockIdx.y * NBX + blockIdx.x;
  const int sbid = (bid & 7) * (NWG / 8) + (bid >> 3);
  const int tm = (sbid / NBX) * 256, tn = (sbid % NBX) * BN;
  const int wm = w / WN, wn = w % WN;
  const int seg = tn >> 10;   // MODE 5 only; tiles never cross a 1024 segment

  f32x4 acc[NI][4] = {};

  const int srow = l >> 3;
  const int sc8 = (l & 7) ^ (srow & 7);
  const unsigned short* Ag = A + (size_t)(tm + srow) * KDIM + sc8 * 8;
  const unsigned short* Bg = B + (size_t)(tn + srow) * KDIM + sc8 * 8;
  // ext-tile sources (stride 64); MODE 5's u depends on the output segment
  const size_t aeoff = (MODE == 5) ? (size_t)seg * MTOT : 0;
  const unsigned short* Ae = HAS_EXT ?
      (Aext + (aeoff + tm + srow) * 64 + sc8 * 8) : nullptr;
  const unsigned short* Be = HAS_EXT ?
      (Bext + (size_t)(tn + srow) * 64 + sc8 * 8) : nullptr;

  const int arow = wm * MSPAN + (l & 15);
  const int bcol = wn * 64 + (l & 15);
  const int kb0 = l >> 4;
  const int swz = l & 7;

  constexpr int NT = KDIM / 64;
  constexpr int TT = HAS_EXT ? NT + 1 : NT;

  auto stage = [&](int buf, int kt) {
    unsigned short* bA = &sAB[buf][0];
    unsigned short* bB = &sAB[buf][256 * 64];
#pragma unroll
    for (int it = 0; it < 4; ++it) {
      const int st = w * 4 + it;
      GLDS(Ag + (size_t)(st * 8) * KDIM + kt, bA + st * 512);
    }
#pragma unroll
    for (int it = 0; it < WN; ++it) {
      const int st = w * WN + it;
      GLDS(Bg + (size_t)(st * 8) * KDIM + kt, bB + st * 512);
    }
  };
  auto stage_ext = [&](int buf) {
    unsigned short* bA = &sAB[buf][0];
    unsigned short* bB = &sAB[buf][256 * 64];
#pragma unroll
    for (int it = 0; it < 4; ++it) {
      const int st = w * 4 + it;
      GLDS(Ae + (size_t)(st * 8) * 64, bA + st * 512);
    }
#pragma unroll
    for (int it = 0; it < WN; ++it) {
      const int st = w * WN + it;
      GLDS(Be + (size_t)(st * 8) * 64, bB + st * 512);
    }
  };

  stage(0, 0);
  asm volatile("s_waitcnt vmcnt(0)" ::: "memory");
  __syncthreads();

  int cur = 0;
  for (int t = 0; t < TT; ++t) {
    const int nt = t + 1;
    if (nt < NT) stage(cur ^ 1, nt * 64);
    else if (HAS_EXT && nt == NT) stage_ext(cur ^ 1);

    const unsigned short* sA_ = &sAB[cur][0];
    const unsigned short* sB_ = &sAB[cur][256 * 64];
#pragma unroll
    for (int kk = 0; kk < 2; ++kk) {
      bf16x8 af[NI], bfv[4];
      const int kphys = ((kk * 4 + kb0) ^ swz) << 3;
#pragma unroll
      for (int i = 0; i < NI; ++i)
        af[i] = *reinterpret_cast<const bf16x8*>(&sA_[(arow + i * 16) * 64 + kphys]);
#pragma unroll
      for (int j = 0; j < 4; ++j)
        bfv[j] = *reinterpret_cast<const bf16x8*>(&sB_[(bcol + j * 16) * 64 + kphys]);
#pragma unroll
      for (int i = 0; i < NI; ++i)
#pragma unroll
        for (int j = 0; j < 4; ++j)
          acc[i][j] = mfma16(af[i], bfv[j], acc[i][j]);
    }
    __syncthreads();
    cur ^= 1;
  }

  const int rbase = tm + wm * MSPAN + ((l >> 4) << 2);
  const int cbase = tn + wn * 64 + (l & 15);

#pragma unroll
  for (int i = 0; i < NI; ++i) {
#pragma unroll
    for (int j = 0; j < 4; ++j) {
      const int col = cbase + j * 16;
      float vv4[4];
#pragma unroll
      for (int r = 0; r < 4; ++r) {
        const int row = rbase + i * 16 + r;
        float v = acc[i][j][r];
        if constexpr (MODE == 2) {
          v += bias[col];
          v = 0.5f * v * (1.f + erff(v * 0.70710678118654752f));
        }
        if constexpr (MODE == 1) {
          v += resid[(size_t)row * NDIM + col];
        }
        if constexpr (MODE == 3) {
          v += bias[col] + resid[(size_t)row * NDIM + col];
        }
        if constexpr (MODE == 5) {
          if (seg == 0) v *= 0.18033688011112042f;  // 0.125 * log2(e)
        }
        vv4[r] = v;
      }
      if constexpr (MODE == 2) {
#pragma unroll
        for (int r = 0; r < 4; ++r)
          ((unsigned short*)outp)[(size_t)(rbase + i * 16 + r) * NDIM + col] = f2bf(vv4[r]);
      } else if constexpr (MODE == 5) {
        const int cl = col & 1023;
        if (seg < 2) {
#pragma unroll
          for (int r = 0; r < 4; ++r)
            ((unsigned short*)outp)[((size_t)seg * MTOT + rbase + i * 16 + r) * D_MODEL + cl] =
                f2bf(vv4[r]);
        } else {
          // vt[b][h][d][t'] key-permuted: token k -> slot (k&15)*4 + ((k>>4)&3)
          const int row0 = rbase + i * 16;
          const int bb = row0 >> 11, t0 = row0 & (SEQ - 1);
          const int hh = cl >> 6, dd = cl & 63;
          const int jj = (t0 >> 4) & 3;
          unsigned short* vb = &((unsigned short*)outp2)[
              (((size_t)bb * NHEADS + hh) * HDIM + dd) * SEQ + (t0 & ~63)];
#pragma unroll
          for (int dlt = 0; dlt < 4; ++dlt)
            vb[((t0 & 15) + dlt) * 4 + jj] = f2bf(vv4[dlt]);
        }
      } else {
#pragma unroll
        for (int r = 0; r < 4; ++r)
          ((float*)outp)[(size_t)(rbase + i * 16 + r) * NDIM + col] = vv4[r];
      }
    }
  }
}

// ---------------------------------------------------------------- flash attention (non-causal)
// Round-15 version: max-free + ones-MFMA softmax, KVBLK=64, 32KB LDS ->
// 4 blocks/CU = 16 waves/CU.
__global__ __launch_bounds__(256, 4) void attn_fwd(const unsigned short* __restrict__ q,
                                                   const unsigned short* __restrict__ k,
                                                   const unsigned short* __restrict__ vt,
                                                   unsigned short* __restrict__ ctx)
{
  __shared__ unsigned short sK[64 * 64];
  __shared__ unsigned short sV[64 * 64];
  __shared__ unsigned short sP[4][32 * 64];

  const int tid = threadIdx.x, w = tid >> 6, l = tid & 63;
  const int lin = blockIdx.y * (SEQ / 128) + blockIdx.x;
  const int W = (lin & 7) * ((BATCH * NHEADS * SEQ / 128) / 8) + (lin >> 3);
  const int bh = W >> 4, b = bh >> 4, hh = bh & 15;
  const int q0 = (W & 15) * 128 + w * 32;
  const size_t base = ((size_t)b * SEQ) * D_MODEL + hh * HDIM;
  const size_t vtbase = (size_t)bh * HDIM * SEQ;

  bf16x8 qf[2][2];
#pragma unroll
  for (int i = 0; i < 2; ++i)
#pragma unroll
    for (int ks = 0; ks < 2; ++ks)
      qf[i][ks] = *reinterpret_cast<const bf16x8*>(
          &q[base + (size_t)(q0 + i * 16 + (l & 15)) * D_MODEL + ks * 32 + (l >> 4) * 8]);

  bf16x8 ones;
#pragma unroll
  for (int e = 0; e < 8; ++e) ones[e] = (__bf16)1.0f;

  f32x4 oacc[2][4] = {};
  f32x4 sumacc[2] = {};

  const int srow8 = l >> 3;
  const int sswz = (l & 7) ^ (srow8 & 7);
  const unsigned short* kg = k + base + (size_t)srow8 * D_MODEL + sswz * 8;
  const unsigned short* vg = vt + vtbase + (size_t)srow8 * SEQ + sswz * 8;

  const int kb0 = l >> 4;
  const int c15 = l & 15;

  for (int kt = 0; kt < SEQ; kt += 64) {
    __syncthreads();
#pragma unroll
    for (int it = 0; it < 2; ++it) {
      const int c = it * 4 + w;
      GLDS(kg + (size_t)(kt + c * 8) * D_MODEL, sK + c * 512);
      GLDS(vg + (size_t)(c * 8) * SEQ + kt, sV + c * 512);
    }
    asm volatile("s_waitcnt vmcnt(0)" ::: "memory");
    __syncthreads();

    // S = Q K^T  (64 keys = 4 j-blocks); scores already in log2 domain
    f32x4 sacc[2][4] = {};
    __builtin_amdgcn_s_setprio(1);
#pragma unroll
    for (int ks = 0; ks < 2; ++ks) {
#pragma unroll
      for (int j = 0; j < 4; ++j) {
        const int row = j * 16 + (l & 15);
        bf16x8 kf = *reinterpret_cast<const bf16x8*>(
            &sK[row * 64 + (((ks * 4 + kb0) ^ (row & 7)) << 3)]);
#pragma unroll
        for (int i = 0; i < 2; ++i) sacc[i][j] = mfma16(qf[i][ks], kf, sacc[i][j]);
      }
    }
    __builtin_amdgcn_s_setprio(0);

    // max-free softmax: p = exp2(s); denominator via ones-MFMA in PV phase.
#pragma unroll
    for (int i = 0; i < 2; ++i) {
#pragma unroll
      for (int r = 0; r < 4; ++r) {
        float p[4];
#pragma unroll
        for (int j = 0; j < 4; ++j) p[j] = __builtin_exp2f(sacc[i][j][r]);
        const int prow = i * 16 + ((l >> 4) << 2) + r;
        u16x4 pk;
        pk[0] = f2bf(p[0]); pk[1] = f2bf(p[1]); pk[2] = f2bf(p[2]); pk[3] = f2bf(p[3]);
        *reinterpret_cast<u16x4*>(
            &sP[w][prow * 64 + ((((c15 >> 1) ^ (prow & 7)) << 3) | ((c15 & 1) << 2))]) = pk;
      }
    }

    // O += P V ; rowsum += P * ones
    __builtin_amdgcn_s_setprio(1);
#pragma unroll
    for (int ks = 0; ks < 2; ++ks) {
      bf16x8 pf[2];
#pragma unroll
      for (int i = 0; i < 2; ++i) {
        const int prw = i * 16 + (l & 15);
        pf[i] = *reinterpret_cast<const bf16x8*>(
            &sP[w][prw * 64 + (((ks * 4 + kb0) ^ (prw & 7)) << 3)]);
      }
#pragma unroll
      for (int j = 0; j < 4; ++j) {
        const int row = j * 16 + (l & 15);
        bf16x8 vf = *reinterpret_cast<const bf16x8*>(
            &sV[row * 64 + (((ks * 4 + kb0) ^ (row & 7)) << 3)]);
#pragma unroll
        for (int i = 0; i < 2; ++i) oacc[i][j] = mfma16(pf[i], vf, oacc[i][j]);
      }
#pragma unroll
      for (int i = 0; i < 2; ++i) sumacc[i] = mfma16(pf[i], ones, sumacc[i]);
    }
    __builtin_amdgcn_s_setprio(0);
  }

#pragma unroll
  for (int i = 0; i < 2; ++i)
#pragma unroll
    for (int r = 0; r < 4; ++r) {
      float inv = 1.f / sumacc[i][r];
      int row = q0 + i * 16 + ((l >> 4) << 2) + r;
#pragma unroll
      for (int j = 0; j < 4; ++j)
        ctx[base + (size_t)row * D_MODEL + j * 16 + (l & 15)] = f2bf(oacc[i][j][r] * inv);
    }
}

// ---------------------------------------------------------------- launch
extern "C" void kernel_launch(void* const* d_in, const int* in_sizes, int n_in,
                              void* d_out, int out_size, void* d_ws, size_t ws_size,
                              hipStream_t stream)
{
  (void)in_sizes; (void)n_in; (void)out_size; (void)ws_size;
  const float* x      = (const float*)d_in[0];
  const float* dyn_q  = (const float*)d_in[1];
  const float* dyn_k  = (const float*)d_in[2];
  const float* dyn_v  = (const float*)d_in[3];
  const float* dyn_f1 = (const float*)d_in[4];
  const float* dyn_f2 = (const float*)d_in[5];
  const float* Wq = (const float*)d_in[6];
  const float* Aq = (const float*)d_in[7];
  const float* Wk = (const float*)d_in[8];
  const float* Ak = (const float*)d_in[9];
  const float* Wv = (const float*)d_in[10];
  const float* Av = (const float*)d_in[11];
  const float* Wo = (const float*)d_in[12];
  const float* W1 = (const float*)d_in[13];
  const float* b1 = (const float*)d_in[14];
  const float* A1 = (const float*)d_in[15];
  const float* W2 = (const float*)d_in[16];
  const float* b2 = (const float*)d_in[17];
  const float* A2 = (const float*)d_in[18];
  const float* g1 = (const float*)d_in[19];
  const float* be1 = (const float*)d_in[20];
  const float* g2 = (const float*)d_in[21];
  const float* be2 = (const float*)d_in[22];

  char* ws = (char*)d_ws;
  size_t o = 0;
  auto take = [&](size_t b) { size_t r = o; o += (b + 255) & ~(size_t)255; return r; };
  const size_t o_wq = take((size_t)D_MODEL * D_MODEL * 2);
  const size_t o_wk = take((size_t)D_MODEL * D_MODEL * 2);
  const size_t o_wv = take((size_t)D_MODEL * D_MODEL * 2);
  const size_t o_wo = take((size_t)D_MODEL * D_MODEL * 2);
  const size_t o_w1 = take((size_t)D_FF * D_MODEL * 2);
  const size_t o_w2 = take((size_t)D_FF * D_MODEL * 2);
  const size_t o_h1 = take((size_t)MTOT * D_MODEL * 2);   // later reused as ctx
  const size_t o_q  = take((size_t)MTOT * D_MODEL * 2);   // q,k contiguous; later x2
  const size_t o_k  = take((size_t)MTOT * D_MODEL * 2);
  const size_t o_v  = take((size_t)MTOT * D_MODEL * 2);   // vt; later reused as h2
  const size_t o_ue = take((size_t)3 * MTOT * 64 * 2);    // uext qkv; later f1/f2
  const size_t o_aq = take((size_t)3 * D_MODEL * 64 * 2); // adext qkv
  const size_t o_a1 = take((size_t)D_FF * 64 * 2);        // adext ff1
  const size_t o_a2 = take((size_t)D_MODEL * 64 * 2);     // adext ff2
  const size_t o_ff = take((size_t)MTOT * D_FF * 2);

  unsigned short* wq_b = (unsigned short*)(ws + o_wq);
  unsigned short* wk_b = (unsigned short*)(ws + o_wk);
  unsigned short* wv_b = (unsigned short*)(ws + o_wv);
  unsigned short* wo_b = (unsigned short*)(ws + o_wo);
  unsigned short* w1_b = (unsigned short*)(ws + o_w1);
  unsigned short* w2_b = (unsigned short*)(ws + o_w2);
  unsigned short* h1   = (unsigned short*)(ws + o_h1);
  unsigned short* qb   = (unsigned short*)(ws + o_q);
  unsigned short* vtb  = (unsigned short*)(ws + o_v);
  unsigned short* ueq  = (unsigned short*)(ws + o_ue);            // uext[3][MTOT][64]
  unsigned short* uef1 = ueq;                                     // reuse after QKV
  unsigned short* uef2 = ueq + (size_t)MTOT * 64;
  unsigned short* adeq = (unsigned short*)(ws + o_aq);
  unsigned short* ade1 = (unsigned short*)(ws + o_a1);
  unsigned short* ade2 = (unsigned short*)(ws + o_a2);
  unsigned short* ctx = h1;                    // reuse
  float* x2 = (float*)(ws + o_q);              // reuse q+k (32MB)
  unsigned short* h2 = vtb;                    // reuse
  unsigned short* ffb = (unsigned short*)(ws + o_ff);

  // 1. weights -> bf16 (single merged launch) + Ad ext tables
  cvt_bf16_all<<<6144, 256, 0, stream>>>(Wq, Wk, Wv, Wo, W1, W2,
                                         wq_b, wk_b, wv_b, wo_b, w1_b, w2_b);
  ad_ext<<<32, 256, 0, stream>>>(Aq, Ak, Av, A1, A2, adeq, ade1, ade2);

  // 2. LN1
  ln_fwd<<<MTOT, 256, 0, stream>>>(x, g1, be1, h1);

  // 3. u-ext for q,k,v (fused, reads h1 once)
  dyn_u_qkv<<<MTOT / 16, 256, 0, stream>>>(h1, dyn_q, dyn_k, dyn_v, ueq);

  // 4. fused QKV projection (BN=256, K-ext; Q pre-scaled, V transposed+key-permuted)
  gemm_bt<3 * D_MODEL, D_MODEL, 5, 256><<<dim3(3 * D_MODEL / 256, MTOT / 256), 512, 0, stream>>>(
      h1, wq_b, qb, vtb, ueq, adeq, nullptr, nullptr);

  // 5. attention
  attn_fwd<<<dim3(SEQ / 128, BATCH * NHEADS), 256, 0, stream>>>(
      qb, qb + (size_t)MTOT * D_MODEL, vtb, ctx);

  // 6. Wo + residual -> x2 (fp32), BN=128, no ext
  gemm_bt<D_MODEL, D_MODEL, 1, 128><<<dim3(D_MODEL / 128, MTOT / 256), 512, 0, stream>>>(
      ctx, wo_b, x2, nullptr, nullptr, nullptr, nullptr, x);

  // 7. LN2
  ln_fwd<<<MTOT, 256, 0, stream>>>(x2, g2, be2, h2);

  // 8. u-ext f1, FF1 (+bias, gelu) -> ff bf16, BN=256, K-ext
  dyn_u<D_MODEL><<<MTOT / 16, 256, 0, stream>>>(h2, dyn_f1, uef1);
  gemm_bt<D_FF, D_MODEL, 2, 256><<<dim3(D_FF / 256, MTOT / 256), 512, 0, stream>>>(
      h2, w1_b, ffb, nullptr, uef1, ade1, b1, nullptr);

  // 9. u-ext f2, FF2 (+bias +resid) -> out fp32, BN=128, K-ext
  dyn_u<D_FF><<<MTOT / 16, 256, 0, stream>>>(ffb, dyn_f2, uef2);
  gemm_bt<D_MODEL, D_FF, 3, 128><<<dim3(D_MODEL / 128, MTOT / 256), 512, 0, stream>>>(
      ffb, w2_b, (float*)d_out, nullptr, uef2, ade2, b2, x2);
}